// Round 1
// baseline (2187.341 us; speedup 1.0000x reference)
//
#include <hip/hip_runtime.h>
#include <math.h>

#define BB 8
#define CC 32
#define NN 4096
#define KNN 32
#define NP (BB*NN)   // 32768

// workspace float offsets
#define OFF_XT  0u
#define OFF_QF  1048576u
#define OFF_KF  2097152u
#define OFF_VN  3145728u
#define OFF_XX  4194304u
#define OFF_IDX 4227072u   // used as unsigned*

__device__ __forceinline__ unsigned fkey(float x) {
    unsigned fb = __float_as_uint(x);
    return (fb & 0x80000000u) ? ~fb : (fb | 0x80000000u);
}

__device__ __forceinline__ float elu1(float x) {
    return x > 0.f ? x + 1.f : expf(x);
}

// ---------------- K1: transpose feat[B,C,N] -> xt[B,N,C] ----------------
__global__ __launch_bounds__(256) void k_transpose(const float* __restrict__ feat,
                                                   float* __restrict__ xt) {
    __shared__ float tile[32][65];
    int b = blockIdx.y;
    int n0 = blockIdx.x * 64;
    int t = threadIdx.x;
    int nn = t & 63, cr = t >> 6;
#pragma unroll
    for (int r = 0; r < 8; ++r) {
        int c = r * 4 + cr;
        tile[c][nn] = feat[((size_t)b * 32 + c) * NN + n0 + nn];
    }
    __syncthreads();
    int c2 = t & 31, nr = t >> 5;
#pragma unroll
    for (int r = 0; r < 8; ++r) {
        int nl = r * 8 + nr;
        xt[((size_t)b * NN + n0 + nl) * 32 + c2] = tile[c2][nl];
    }
}

// ---------------- K2: per-point prep ----------------
__global__ __launch_bounds__(256, 2) void k_prep(
        const float* __restrict__ xt, const float* __restrict__ xyz,
        const float* __restrict__ w_pos1, const float* __restrict__ b_pos1,
        const float* __restrict__ w_pos2, const float* __restrict__ b_pos2,
        const float* __restrict__ w_q, const float* __restrict__ w_k,
        const float* __restrict__ w_v,
        float* __restrict__ Qf, float* __restrict__ Kf, float* __restrict__ Vn,
        float* __restrict__ xx) {
    int lane = threadIdx.x & 31;
    int g = threadIdx.x >> 5;
    float w1c0 = w_pos1[lane], w1c1 = w_pos1[32 + lane], w1c2 = w_pos1[64 + lane];
    float b1c = b_pos1[lane], b2c = b_pos2[lane];
    float w2c[32], wqc[32], wkc[32], wvc[32];
#pragma unroll
    for (int j = 0; j < 32; ++j) {
        w2c[j] = w_pos2[j * 32 + lane];
        wqc[j] = w_q[j * 32 + lane];
        wkc[j] = w_k[j * 32 + lane];
        wvc[j] = w_v[j * 32 + lane];
    }
    for (int p = blockIdx.x * 8 + g; p < NP; p += gridDim.x * 8) {
        float x0 = xyz[(size_t)p * 3 + 0];
        float x1 = xyz[(size_t)p * 3 + 1];
        float x2 = xyz[(size_t)p * 3 + 2];
        float h = fmaxf(x0 * w1c0 + x1 * w1c1 + x2 * w1c2 + b1c, 0.f);
        float P = b2c;
#pragma unroll
        for (int j = 0; j < 32; ++j) P += __shfl(h, j, 32) * w2c[j];
        float xv = xt[(size_t)p * 32 + lane];
        float qin = xv + P;
        float s = xv * xv;
#pragma unroll
        for (int m = 16; m >= 1; m >>= 1) s += __shfl_xor(s, m, 32);
        if (lane == 0) xx[p] = s;
        float qa = 0.f, ka = 0.f, va = 0.f;
#pragma unroll
        for (int j = 0; j < 32; ++j) {
            float qj = __shfl(qin, j, 32);
            qa += qj * wqc[j];
            ka += qj * wkc[j];
            va += qj * wvc[j];
        }
        Qf[(size_t)p * 32 + lane] = elu1(qa);
        Kf[(size_t)p * 32 + lane] = elu1(ka);
        Vn[(size_t)p * 32 + lane] = va;   // raw V ((V/k)*k cancels exactly, pow2)
    }
}

// ---------------- K3: KNN (4 rows/block, exact top-32 radix select) ----------------
__global__ __launch_bounds__(256, 2) void k_knn(const float* __restrict__ feat,
                                                const float* __restrict__ xt,
                                                const float* __restrict__ xx,
                                                unsigned* __restrict__ idxg) {
    __shared__ float sc[4][4096];   // exactly 64 KB; tail of each row reused for hist/out
    int b = blockIdx.y;
    int n0 = blockIdx.x * 4;
    int t = threadIdx.x;
    const float* xtb = xt + ((size_t)b * NN + n0) * 32;
    float xr[4][32];
#pragma unroll
    for (int r = 0; r < 4; ++r)
#pragma unroll
        for (int c = 0; c < 32; c += 4) {
            float4 v = *(const float4*)&xtb[r * 32 + c];
            xr[r][c] = v.x; xr[r][c + 1] = v.y; xr[r][c + 2] = v.z; xr[r][c + 3] = v.w;
        }
    float xxr[4];
#pragma unroll
    for (int r = 0; r < 4; ++r) xxr[r] = xx[b * NN + n0 + r];
    const float* fb = feat + (size_t)b * 32 * NN;
    const float* xxb = xx + b * NN;
    for (int tile = 0; tile < 16; ++tile) {
        int j = tile * 256 + t;
        float a0 = 0.f, a1 = 0.f, a2 = 0.f, a3 = 0.f;
#pragma unroll
        for (int c = 0; c < 32; ++c) {
            float f = fb[(size_t)c * NN + j];
            a0 += xr[0][c] * f; a1 += xr[1][c] * f;
            a2 += xr[2][c] * f; a3 += xr[3][c] * f;
        }
        float xxj = xxb[j];
        sc[0][j] = (2.f * a0 - xxr[0]) - xxj;
        sc[1][j] = (2.f * a1 - xxr[1]) - xxj;
        sc[2][j] = (2.f * a2 - xxr[2]) - xxj;
        sc[3][j] = (2.f * a3 - xxr[3]) - xxj;
    }
    __syncthreads();

    // selection: wave w handles row w
    int w = t >> 6, lane = t & 63;
    float* srow = sc[w];
    // evict the last 3 element-blocks into registers; carve scratch there
    float r61 = srow[61 * 64 + lane];
    float r62 = srow[62 * 64 + lane];
    float r63 = srow[63 * 64 + lane];
    __syncthreads();
    unsigned* H   = (unsigned*)(srow + 3904);  // 128 u32 = 256 packed u16 buckets
    unsigned* O   = (unsigned*)(srow + 4032);  // 32 selected indices
    unsigned* CNT = (unsigned*)(srow + 4064);
    if (lane == 0) *CNT = 0;
    unsigned prefix = 0;
    int need = 32;
#pragma unroll 1
    for (int level = 0; level < 4; ++level) {
        int shift = 24 - 8 * level;
        H[lane] = 0; H[64 + lane] = 0;
        __syncthreads();
        for (int i = 0; i < 61; ++i) {
            unsigned u = fkey(srow[i * 64 + lane]);
            if (level == 0 || (u >> (shift + 8)) == prefix) {
                unsigned bkt = (u >> shift) & 255u;
                atomicAdd(&H[bkt >> 1], 1u << ((bkt & 1) * 16));
            }
        }
        {
            float ev[3] = {r61, r62, r63};
#pragma unroll
            for (int q2 = 0; q2 < 3; ++q2) {
                unsigned u = fkey(ev[q2]);
                if (level == 0 || (u >> (shift + 8)) == prefix) {
                    unsigned bkt = (u >> shift) & 255u;
                    atomicAdd(&H[bkt >> 1], 1u << ((bkt & 1) * 16));
                }
            }
        }
        __syncthreads();
        // suffix scan over 256 buckets (lane owns buckets 4l..4l+3)
        unsigned wd0 = H[2 * lane], wd1 = H[2 * lane + 1];
        unsigned h0 = wd0 & 0xffffu, h1 = wd0 >> 16;
        unsigned h2 = wd1 & 0xffffu, h3 = wd1 >> 16;
        unsigned ssum = h0 + h1 + h2 + h3;
        unsigned acc = ssum;
#pragma unroll
        for (int off = 1; off < 64; off <<= 1) {
            unsigned vv = __shfl_down(acc, off, 64);
            if (lane + off < 64) acc += vv;
        }
        unsigned Sx = acc - ssum;   // strict suffix over lanes
        unsigned A3 = Sx, A2 = Sx + h3, A1 = A2 + h2, A0 = A1 + h1;
        unsigned un = (unsigned)need;
        int qsel = -1; unsigned Asel = 0;
        if      (A0 < un && un <= A0 + h0) { qsel = 0; Asel = A0; }
        else if (A1 < un && un <= A1 + h1) { qsel = 1; Asel = A1; }
        else if (A2 < un && un <= A2 + h2) { qsel = 2; Asel = A2; }
        else if (A3 < un && un <= A3 + h3) { qsel = 3; Asel = A3; }
        unsigned long long bal = __ballot(qsel >= 0);
        int wl = __ffsll(bal) - 1;
        int vstar = __shfl(qsel, wl, 64) + 4 * wl;
        unsigned Astar = (unsigned)__shfl((int)Asel, wl, 64);
        // emit certainly-in elements (bucket > vstar)
        for (int i = 0; i < 61; ++i) {
            unsigned u = fkey(srow[i * 64 + lane]);
            bool match = (level == 0) || ((u >> (shift + 8)) == prefix);
            if (match && (int)((u >> shift) & 255u) > vstar) {
                unsigned pos = atomicAdd(CNT, 1u);
                O[pos] = (unsigned)(i * 64 + lane);
            }
        }
        {
            float ev[3] = {r61, r62, r63};
#pragma unroll
            for (int q2 = 0; q2 < 3; ++q2) {
                unsigned u = fkey(ev[q2]);
                bool match = (level == 0) || ((u >> (shift + 8)) == prefix);
                if (match && (int)((u >> shift) & 255u) > vstar) {
                    unsigned pos = atomicAdd(CNT, 1u);
                    O[pos] = (unsigned)((61 + q2) * 64 + lane);
                }
            }
        }
        prefix = (prefix << 8) | (unsigned)vstar;
        need -= (int)Astar;
        __syncthreads();
    }
    // ties at exact threshold key: take lowest indices (matches top_k stability)
    unsigned T = prefix;
    int base = 32 - need;
    for (int i = 0; i < 64 && need > 0; ++i) {
        float v = (i < 61) ? srow[i * 64 + lane]
                           : (i == 61 ? r61 : (i == 62 ? r62 : r63));
        unsigned u = fkey(v);
        bool m = (u == T);
        unsigned long long bal = __ballot(m);
        int rk = __popcll(bal & ((1ull << lane) - 1ull));
        if (m && rk < need) O[base + rk] = (unsigned)(i * 64 + lane);
        int c = __popcll(bal);
        int take = c < need ? c : need;
        base += take; need -= take;
    }
    __syncthreads();
    if (lane < 32) idxg[((size_t)b * NN + n0 + w) * 32 + lane] = O[lane];
}

// ---------------- K4: attention + merge + LN + MLP + LN + residual ----------------
__global__ __launch_bounds__(256, 2) void k_attn(
        const float* __restrict__ xt,
        const float* __restrict__ Qf, const float* __restrict__ Kf,
        const float* __restrict__ Vn, const unsigned* __restrict__ idxg,
        const float* __restrict__ w_merge,
        const float* __restrict__ ln1_g, const float* __restrict__ ln1_b,
        const float* __restrict__ w_mlp1, const float* __restrict__ w_mlp2,
        const float* __restrict__ ln2_g, const float* __restrict__ ln2_b,
        float* __restrict__ out) {
    __shared__ float wmL[32][32];
    __shared__ float w1L[64][64];
    __shared__ float w2L[64][32];
    __shared__ float otile[32][33];
    int t = threadIdx.x;
    for (int i = t; i < 1024; i += 256) wmL[i >> 5][i & 31] = w_merge[i];
    for (int i = t; i < 4096; i += 256) w1L[i >> 6][i & 63] = w_mlp1[i];
    for (int i = t; i < 2048; i += 256) w2L[i >> 5][i & 31] = w_mlp2[i];
    int lane = t & 31, g = t >> 5;
    float l1g = ln1_g[lane], l1b = ln1_b[lane];
    float l2g = ln2_g[lane], l2b = ln2_b[lane];
    __syncthreads();
    int p0 = blockIdx.x * 32;
    int b = p0 / NN;
    size_t bbase = (size_t)b * NN;
    for (int i = 0; i < 4; ++i) {
        int p = p0 + i * 8 + g;
        size_t pb = (size_t)p * 32;
        float q = Qf[pb + lane];
        float x = xt[pb + lane];
        float zacc = 0.f, macc = 0.f;
        for (int k = 0; k < 32; ++k) {
            int j = (int)idxg[pb + k];
            size_t jb = (bbase + (size_t)j) * 32;
            float kf = Kf[jb + lane];
            float vn = Vn[jb + lane];
            float s = q * kf;
            s += __shfl_xor(s, 1, 8);
            s += __shfl_xor(s, 2, 8);
            s += __shfl_xor(s, 4, 8);
            zacc += s;
            macc += s * vn;
        }
        float Z = 1.f / (zacc + 1e-6f);
        float msg = macc * Z;
        float mo = 0.f;
#pragma unroll
        for (int c = 0; c < 32; ++c) mo += __shfl(msg, c, 32) * wmL[c][lane];
        float mean = mo;
#pragma unroll
        for (int m = 16; m >= 1; m >>= 1) mean += __shfl_xor(mean, m, 32);
        mean *= (1.f / 32.f);
        float d = mo - mean;
        float var = d * d;
#pragma unroll
        for (int m = 16; m >= 1; m >>= 1) var += __shfl_xor(var, m, 32);
        var *= (1.f / 32.f);
        float msgn = l1g * d * rsqrtf(var + 1e-5f) + l1b;
        float h0 = 0.f, h1 = 0.f;
#pragma unroll
        for (int c = 0; c < 32; ++c) {
            float xc = __shfl(x, c, 32);
            float mc = __shfl(msgn, c, 32);
            h0 += xc * w1L[c][lane]      + mc * w1L[c + 32][lane];
            h1 += xc * w1L[c][lane + 32] + mc * w1L[c + 32][lane + 32];
        }
        h0 = fmaxf(h0, 0.f); h1 = fmaxf(h1, 0.f);
        float o = 0.f;
#pragma unroll
        for (int c = 0; c < 32; ++c) {
            o += __shfl(h0, c, 32) * w2L[c][lane] + __shfl(h1, c, 32) * w2L[c + 32][lane];
        }
        float mean2 = o;
#pragma unroll
        for (int m = 16; m >= 1; m >>= 1) mean2 += __shfl_xor(mean2, m, 32);
        mean2 *= (1.f / 32.f);
        float d2 = o - mean2;
        float var2 = d2 * d2;
#pragma unroll
        for (int m = 16; m >= 1; m >>= 1) var2 += __shfl_xor(var2, m, 32);
        var2 *= (1.f / 32.f);
        float on = l2g * d2 * rsqrtf(var2 + 1e-5f) + l2b;
        otile[lane][i * 8 + g] = x + on;
    }
    __syncthreads();
    int nn = t & 31, cr = t >> 5;
    int nb = p0 % NN;
#pragma unroll
    for (int r = 0; r < 4; ++r) {
        int c = r * 8 + cr;
        out[((size_t)b * 32 + c) * NN + nb + nn] = otile[c][nn];
    }
}

extern "C" void kernel_launch(void* const* d_in, const int* in_sizes, int n_in,
                              void* d_out, int out_size, void* d_ws, size_t ws_size,
                              hipStream_t stream) {
    const float* feat   = (const float*)d_in[0];
    const float* xyz    = (const float*)d_in[1];
    const float* w_pos1 = (const float*)d_in[2];
    const float* b_pos1 = (const float*)d_in[3];
    const float* w_pos2 = (const float*)d_in[4];
    const float* b_pos2 = (const float*)d_in[5];
    const float* w_q    = (const float*)d_in[6];
    const float* w_k    = (const float*)d_in[7];
    const float* w_v    = (const float*)d_in[8];
    const float* w_mg   = (const float*)d_in[9];
    const float* ln1_g  = (const float*)d_in[10];
    const float* ln1_b  = (const float*)d_in[11];
    const float* w_mlp1 = (const float*)d_in[12];
    const float* w_mlp2 = (const float*)d_in[13];
    const float* ln2_g  = (const float*)d_in[14];
    const float* ln2_b  = (const float*)d_in[15];
    float* ws = (float*)d_ws;
    float* xt = ws + OFF_XT;
    float* Qf = ws + OFF_QF;
    float* Kf = ws + OFF_KF;
    float* Vn = ws + OFF_VN;
    float* xx = ws + OFF_XX;
    unsigned* idxg = (unsigned*)(ws + OFF_IDX);
    float* out = (float*)d_out;

    k_transpose<<<dim3(64, 8), 256, 0, stream>>>(feat, xt);
    k_prep<<<1024, 256, 0, stream>>>(xt, xyz, w_pos1, b_pos1, w_pos2, b_pos2,
                                     w_q, w_k, w_v, Qf, Kf, Vn, xx);
    k_knn<<<dim3(1024, 8), 256, 0, stream>>>(feat, xt, xx, idxg);
    k_attn<<<1024, 256, 0, stream>>>(xt, Qf, Kf, Vn, idxg, w_mg, ln1_g, ln1_b,
                                     w_mlp1, w_mlp2, ln2_g, ln2_b, out);
}

// Round 2
// 1287.117 us; speedup vs baseline: 1.6994x; 1.6994x over previous
//
#include <hip/hip_runtime.h>
#include <math.h>

#define BB 8
#define CC 32
#define NN 4096
#define KNN 32
#define NP (BB*NN)   // 32768

// workspace float offsets
#define OFF_XT  0u
#define OFF_QF  1048576u
#define OFF_KF  2097152u
#define OFF_VN  3145728u
#define OFF_XX  4194304u
#define OFF_IDX 4227072u   // used as unsigned*

__device__ __forceinline__ float elu1(float x) {
    return x > 0.f ? x + 1.f : expf(x);
}

// ---------------- K1: transpose feat[B,C,N] -> xt[B,N,C] ----------------
__global__ __launch_bounds__(256) void k_transpose(const float* __restrict__ feat,
                                                   float* __restrict__ xt) {
    __shared__ float tile[32][65];
    int b = blockIdx.y;
    int n0 = blockIdx.x * 64;
    int t = threadIdx.x;
    int nn = t & 63, cr = t >> 6;
#pragma unroll
    for (int r = 0; r < 8; ++r) {
        int c = r * 4 + cr;
        tile[c][nn] = feat[((size_t)b * 32 + c) * NN + n0 + nn];
    }
    __syncthreads();
    int c2 = t & 31, nr = t >> 5;
#pragma unroll
    for (int r = 0; r < 8; ++r) {
        int nl = r * 8 + nr;
        xt[((size_t)b * NN + n0 + nl) * 32 + c2] = tile[c2][nl];
    }
}

// ---------------- K2: per-point prep ----------------
__global__ __launch_bounds__(256, 2) void k_prep(
        const float* __restrict__ xt, const float* __restrict__ xyz,
        const float* __restrict__ w_pos1, const float* __restrict__ b_pos1,
        const float* __restrict__ w_pos2, const float* __restrict__ b_pos2,
        const float* __restrict__ w_q, const float* __restrict__ w_k,
        const float* __restrict__ w_v,
        float* __restrict__ Qf, float* __restrict__ Kf, float* __restrict__ Vn,
        float* __restrict__ xx) {
    int lane = threadIdx.x & 31;
    int g = threadIdx.x >> 5;
    float w1c0 = w_pos1[lane], w1c1 = w_pos1[32 + lane], w1c2 = w_pos1[64 + lane];
    float b1c = b_pos1[lane], b2c = b_pos2[lane];
    float w2c[32], wqc[32], wkc[32], wvc[32];
#pragma unroll
    for (int j = 0; j < 32; ++j) {
        w2c[j] = w_pos2[j * 32 + lane];
        wqc[j] = w_q[j * 32 + lane];
        wkc[j] = w_k[j * 32 + lane];
        wvc[j] = w_v[j * 32 + lane];
    }
    for (int p = blockIdx.x * 8 + g; p < NP; p += gridDim.x * 8) {
        float x0 = xyz[(size_t)p * 3 + 0];
        float x1 = xyz[(size_t)p * 3 + 1];
        float x2 = xyz[(size_t)p * 3 + 2];
        float h = fmaxf(x0 * w1c0 + x1 * w1c1 + x2 * w1c2 + b1c, 0.f);
        float P = b2c;
#pragma unroll
        for (int j = 0; j < 32; ++j) P += __shfl(h, j, 32) * w2c[j];
        float xv = xt[(size_t)p * 32 + lane];
        float qin = xv + P;
        float s = xv * xv;
#pragma unroll
        for (int m = 16; m >= 1; m >>= 1) s += __shfl_xor(s, m, 32);
        if (lane == 0) xx[p] = s;
        float qa = 0.f, ka = 0.f, va = 0.f;
#pragma unroll
        for (int j = 0; j < 32; ++j) {
            float qj = __shfl(qin, j, 32);
            qa += qj * wqc[j];
            ka += qj * wkc[j];
            va += qj * wvc[j];
        }
        Qf[(size_t)p * 32 + lane] = elu1(qa);
        Kf[(size_t)p * 32 + lane] = elu1(ka);
        Vn[(size_t)p * 32 + lane] = va;   // raw V ((V/k)*k cancels exactly, pow2)
    }
}

// ---------------- K3: KNN — quantized single-pass histogram select ----------------
// Block: 256 threads (4 waves), 4 rows; wave w selects row w.
// Score layout (swizzled): col j = L*64+o stored at sc[r][L*64 + (o ^ (L&31))]
// so lane L owns cols [L*64, L*64+64) and reads are 2-way bank-free.
__global__ __launch_bounds__(256, 2) void k_knn(const float* __restrict__ feat,
                                                const float* __restrict__ xt,
                                                const float* __restrict__ xx,
                                                unsigned* __restrict__ idxg) {
    __shared__ float sc[4][4096];      // 64 KB
    __shared__ unsigned Hh[4][576];    // 1024 u16 buckets packed + 1/8 pad, per wave
    __shared__ unsigned Oo[4][32];
    int bid = blockIdx.x;
    int b = bid & 7;                   // XCD-swizzle: XCD k keeps batch k in its L2
    int n0 = (bid >> 3) << 2;
    int t = threadIdx.x;

    // ---- distance compute: 4 rows x 4096 cols ----
    const float* xtb = xt + ((size_t)b * NN + n0) * 32;
    float xr[4][32];
#pragma unroll
    for (int r = 0; r < 4; ++r)
#pragma unroll
        for (int c = 0; c < 32; c += 4) {
            float4 v4 = *(const float4*)&xtb[r * 32 + c];
            xr[r][c] = v4.x; xr[r][c + 1] = v4.y; xr[r][c + 2] = v4.z; xr[r][c + 3] = v4.w;
        }
    float xxr[4];
#pragma unroll
    for (int r = 0; r < 4; ++r) xxr[r] = xx[b * NN + n0 + r];
    const float* fb = feat + (size_t)b * 32 * NN;
    const float* xxb = xx + (size_t)b * NN;
    for (int tile = 0; tile < 16; ++tile) {
        int j = tile * 256 + t;
        float a0 = 0.f, a1 = 0.f, a2 = 0.f, a3 = 0.f;
#pragma unroll
        for (int c = 0; c < 32; ++c) {
            float f = fb[(size_t)c * NN + j];
            a0 += xr[0][c] * f; a1 += xr[1][c] * f;
            a2 += xr[2][c] * f; a3 += xr[3][c] * f;
        }
        float xxj = xxb[j];
        int L = j >> 6, o = j & 63;
        int ad = L * 64 + (o ^ (L & 31));
        sc[0][ad] = (2.f * a0 - xxr[0]) - xxj;
        sc[1][ad] = (2.f * a1 - xxr[1]) - xxj;
        sc[2][ad] = (2.f * a2 - xxr[2]) - xxj;
        sc[3][ad] = (2.f * a3 - xxr[3]) - xxj;
    }
    __syncthreads();

    // ---- selection: wave w handles row w ----
    int w = t >> 6, lane = t & 63;
    float* srow = sc[w];
    unsigned* Hb = Hh[w];
    unsigned* Ob = Oo[w];
    int cxor = lane & 31;
    int abase = lane * 64;

    float v[64];
#pragma unroll
    for (int o = 0; o < 64; ++o) v[o] = srow[abase + (o ^ cxor)];

    float mn = v[0], mx = v[0];
#pragma unroll
    for (int o = 1; o < 64; ++o) { mn = fminf(mn, v[o]); mx = fmaxf(mx, v[o]); }
#pragma unroll
    for (int off = 32; off >= 1; off >>= 1) {
        mn = fminf(mn, __shfl_xor(mn, off, 64));
        mx = fmaxf(mx, __shfl_xor(mx, off, 64));
    }
    float range = mx - mn;
    float scale = (range > 1e-20f) ? (1021.0f / range) : 0.f;
    int u[64];
#pragma unroll
    for (int o = 0; o < 64; ++o) {
        int q = (int)((v[o] - mn) * scale);
        q = q < 0 ? 0 : (q > 1023 ? 1023 : q);
        u[o] = q;
    }

    // zero per-wave histogram (576 = 64*9 words)
#pragma unroll
    for (int i = 0; i < 9; ++i) Hb[lane + 64 * i] = 0u;
    __syncthreads();
    // histogram: bucket q -> halfword q; word q>>1; padded word += word>>3
#pragma unroll
    for (int o = 0; o < 64; ++o) {
        unsigned q = (unsigned)u[o];
        unsigned wd = q >> 1;
        unsigned pw = wd + (wd >> 3);
        atomicAdd(&Hb[pw], 1u << ((q & 1u) * 16u));
    }
    __syncthreads();

    // suffix scan: lane L owns buckets [L*16, L*16+16)
    unsigned cvals[16];
#pragma unroll
    for (int i2 = 0; i2 < 8; ++i2) {
        unsigned wd = Hb[lane * 9 + i2];
        cvals[2 * i2]     = wd & 0xffffu;
        cvals[2 * i2 + 1] = wd >> 16;
    }
    unsigned ssum = 0;
#pragma unroll
    for (int i = 0; i < 16; ++i) ssum += cvals[i];
    unsigned acc = ssum;
#pragma unroll
    for (int off = 1; off < 64; off <<= 1) {
        unsigned vv = __shfl_down(acc, off, 64);
        if (lane + off < 64) acc += vv;
    }
    unsigned S_above = acc - ssum;   // count in buckets owned by higher lanes
    int Tl = -1; unsigned basel = 0; unsigned running = S_above;
#pragma unroll
    for (int i = 15; i >= 0; --i) {
        unsigned c = cvals[i];
        unsigned nr = running + c;
        if (Tl < 0 && running < 32u && nr >= 32u) { Tl = lane * 16 + i; basel = running; }
        running = nr;
    }
    unsigned long long bal = __ballot(Tl >= 0);
    int src = __ffsll(bal) - 1;
    int T = __shfl(Tl, src, 64);
    unsigned base = (unsigned)__shfl((int)basel, src, 64);

    // emit certainly-in (u > T) via ballot compaction — no atomics
    unsigned cnt_run = 0;
#pragma unroll
    for (int o = 0; o < 64; ++o) {
        bool p = (u[o] > T);
        unsigned long long bm = __ballot(p);
        if (p) {
            unsigned pos = cnt_run + (unsigned)__popcll(bm & ((1ull << lane) - 1ull));
            Ob[pos] = (unsigned)(abase + o);
        }
        cnt_run += (unsigned)__popcll(bm);
    }

    // boundary bucket: exact (value desc, index asc) extraction of remaining
    unsigned long long mask = 0ull;
#pragma unroll
    for (int o = 0; o < 64; ++o) if (u[o] == T) mask |= (1ull << o);
    int need = 32 - (int)base;
    while (need > 0) {
        float bv = -INFINITY; int bj = 1 << 30;
        unsigned long long m2 = mask;
        while (m2) {
            int o = (int)__ffsll(m2) - 1;
            m2 &= m2 - 1ull;
            float vv = srow[abase + (o ^ cxor)];   // LDS re-read: dynamic index
            if (vv > bv) { bv = vv; bj = abase + o; }
        }
#pragma unroll
        for (int off = 1; off < 64; off <<= 1) {
            float ov = __shfl_xor(bv, off, 64);
            int oj = __shfl_xor(bj, off, 64);
            if (ov > bv || (ov == bv && oj < bj)) { bv = ov; bj = oj; }
        }
        if ((bj >> 6) == lane) mask &= ~(1ull << (bj & 63));
        if (lane == 0) Ob[32 - need] = (unsigned)bj;
        --need;
    }
    __syncthreads();
    if (lane < 32) idxg[((size_t)b * NN + n0 + w) * 32 + lane] = Ob[lane];
}

// ---------------- K4: attention + merge + LN + MLP + LN + residual ----------------
__global__ __launch_bounds__(256, 2) void k_attn(
        const float* __restrict__ xt,
        const float* __restrict__ Qf, const float* __restrict__ Kf,
        const float* __restrict__ Vn, const unsigned* __restrict__ idxg,
        const float* __restrict__ w_merge,
        const float* __restrict__ ln1_g, const float* __restrict__ ln1_b,
        const float* __restrict__ w_mlp1, const float* __restrict__ w_mlp2,
        const float* __restrict__ ln2_g, const float* __restrict__ ln2_b,
        float* __restrict__ out) {
    __shared__ float wmL[32][32];
    __shared__ float w1L[64][64];
    __shared__ float w2L[64][32];
    __shared__ float otile[32][33];
    int t = threadIdx.x;
    for (int i = t; i < 1024; i += 256) wmL[i >> 5][i & 31] = w_merge[i];
    for (int i = t; i < 4096; i += 256) w1L[i >> 6][i & 63] = w_mlp1[i];
    for (int i = t; i < 2048; i += 256) w2L[i >> 5][i & 31] = w_mlp2[i];
    int lane = t & 31, g = t >> 5;
    float l1g = ln1_g[lane], l1b = ln1_b[lane];
    float l2g = ln2_g[lane], l2b = ln2_b[lane];
    __syncthreads();
    int p0 = blockIdx.x * 32;
    int b = p0 / NN;
    size_t bbase = (size_t)b * NN;
    for (int i = 0; i < 4; ++i) {
        int p = p0 + i * 8 + g;
        size_t pb = (size_t)p * 32;
        float q = Qf[pb + lane];
        float x = xt[pb + lane];
        float zacc = 0.f, macc = 0.f;
        for (int k = 0; k < 32; ++k) {
            int j = (int)idxg[pb + k];
            size_t jb = (bbase + (size_t)j) * 32;
            float kf = Kf[jb + lane];
            float vn = Vn[jb + lane];
            float s = q * kf;
            s += __shfl_xor(s, 1, 8);
            s += __shfl_xor(s, 2, 8);
            s += __shfl_xor(s, 4, 8);
            zacc += s;
            macc += s * vn;
        }
        float Z = 1.f / (zacc + 1e-6f);
        float msg = macc * Z;
        float mo = 0.f;
#pragma unroll
        for (int c = 0; c < 32; ++c) mo += __shfl(msg, c, 32) * wmL[c][lane];
        float mean = mo;
#pragma unroll
        for (int m = 16; m >= 1; m >>= 1) mean += __shfl_xor(mean, m, 32);
        mean *= (1.f / 32.f);
        float d = mo - mean;
        float var = d * d;
#pragma unroll
        for (int m = 16; m >= 1; m >>= 1) var += __shfl_xor(var, m, 32);
        var *= (1.f / 32.f);
        float msgn = l1g * d * rsqrtf(var + 1e-5f) + l1b;
        float h0 = 0.f, h1 = 0.f;
#pragma unroll
        for (int c = 0; c < 32; ++c) {
            float xc = __shfl(x, c, 32);
            float mc = __shfl(msgn, c, 32);
            h0 += xc * w1L[c][lane]      + mc * w1L[c + 32][lane];
            h1 += xc * w1L[c][lane + 32] + mc * w1L[c + 32][lane + 32];
        }
        h0 = fmaxf(h0, 0.f); h1 = fmaxf(h1, 0.f);
        float o = 0.f;
#pragma unroll
        for (int c = 0; c < 32; ++c) {
            o += __shfl(h0, c, 32) * w2L[c][lane] + __shfl(h1, c, 32) * w2L[c + 32][lane];
        }
        float mean2 = o;
#pragma unroll
        for (int m = 16; m >= 1; m >>= 1) mean2 += __shfl_xor(mean2, m, 32);
        mean2 *= (1.f / 32.f);
        float d2 = o - mean2;
        float var2 = d2 * d2;
#pragma unroll
        for (int m = 16; m >= 1; m >>= 1) var2 += __shfl_xor(var2, m, 32);
        var2 *= (1.f / 32.f);
        float on = l2g * d2 * rsqrtf(var2 + 1e-5f) + l2b;
        otile[lane][i * 8 + g] = x + on;
    }
    __syncthreads();
    int nn = t & 31, cr = t >> 5;
    int nb = p0 % NN;
#pragma unroll
    for (int r = 0; r < 4; ++r) {
        int c = r * 8 + cr;
        out[((size_t)b * 32 + c) * NN + nb + nn] = otile[c][nn];
    }
}

extern "C" void kernel_launch(void* const* d_in, const int* in_sizes, int n_in,
                              void* d_out, int out_size, void* d_ws, size_t ws_size,
                              hipStream_t stream) {
    const float* feat   = (const float*)d_in[0];
    const float* xyz    = (const float*)d_in[1];
    const float* w_pos1 = (const float*)d_in[2];
    const float* b_pos1 = (const float*)d_in[3];
    const float* w_pos2 = (const float*)d_in[4];
    const float* b_pos2 = (const float*)d_in[5];
    const float* w_q    = (const float*)d_in[6];
    const float* w_k    = (const float*)d_in[7];
    const float* w_v    = (const float*)d_in[8];
    const float* w_mg   = (const float*)d_in[9];
    const float* ln1_g  = (const float*)d_in[10];
    const float* ln1_b  = (const float*)d_in[11];
    const float* w_mlp1 = (const float*)d_in[12];
    const float* w_mlp2 = (const float*)d_in[13];
    const float* ln2_g  = (const float*)d_in[14];
    const float* ln2_b  = (const float*)d_in[15];
    float* ws = (float*)d_ws;
    float* xt = ws + OFF_XT;
    float* Qf = ws + OFF_QF;
    float* Kf = ws + OFF_KF;
    float* Vn = ws + OFF_VN;
    float* xx = ws + OFF_XX;
    unsigned* idxg = (unsigned*)(ws + OFF_IDX);
    float* out = (float*)d_out;

    k_transpose<<<dim3(64, 8), 256, 0, stream>>>(feat, xt);
    k_prep<<<1024, 256, 0, stream>>>(xt, xyz, w_pos1, b_pos1, w_pos2, b_pos2,
                                     w_q, w_k, w_v, Qf, Kf, Vn, xx);
    k_knn<<<8192, 256, 0, stream>>>(feat, xt, xx, idxg);
    k_attn<<<1024, 256, 0, stream>>>(xt, Qf, Kf, Vn, idxg, w_mg, ln1_g, ln1_b,
                                     w_mlp1, w_mlp2, ln2_g, ln2_b, out);
}

// Round 3
// 692.459 us; speedup vs baseline: 3.1588x; 1.8588x over previous
//
#include <hip/hip_runtime.h>
#include <math.h>

#define BB 8
#define CC 32
#define NN 4096
#define KNN 32
#define NP (BB*NN)   // 32768

// workspace float offsets
#define OFF_XT  0u
#define OFF_QF  1048576u
#define OFF_KF  2097152u
#define OFF_VN  3145728u
#define OFF_XX  4194304u
#define OFF_IDX 4227072u   // used as unsigned*

__device__ __forceinline__ float elu1(float x) {
    return x > 0.f ? x + 1.f : expf(x);
}

// ---------------- K1: transpose feat[B,C,N] -> xt[B,N,C] ----------------
__global__ __launch_bounds__(256) void k_transpose(const float* __restrict__ feat,
                                                   float* __restrict__ xt) {
    __shared__ float tile[32][65];
    int b = blockIdx.y;
    int n0 = blockIdx.x * 64;
    int t = threadIdx.x;
    int nn = t & 63, cr = t >> 6;
#pragma unroll
    for (int r = 0; r < 8; ++r) {
        int c = r * 4 + cr;
        tile[c][nn] = feat[((size_t)b * 32 + c) * NN + n0 + nn];
    }
    __syncthreads();
    int c2 = t & 31, nr = t >> 5;
#pragma unroll
    for (int r = 0; r < 8; ++r) {
        int nl = r * 8 + nr;
        xt[((size_t)b * NN + n0 + nl) * 32 + c2] = tile[c2][nl];
    }
}

// ---------------- K2: per-point prep (weights in LDS — no spills) ----------------
__global__ __launch_bounds__(256, 2) void k_prep(
        const float* __restrict__ xt, const float* __restrict__ xyz,
        const float* __restrict__ w_pos1, const float* __restrict__ b_pos1,
        const float* __restrict__ w_pos2, const float* __restrict__ b_pos2,
        const float* __restrict__ w_q, const float* __restrict__ w_k,
        const float* __restrict__ w_v,
        float* __restrict__ Qf, float* __restrict__ Kf, float* __restrict__ Vn,
        float* __restrict__ xx) {
    __shared__ float sW2[1024], sWq[1024], sWk[1024], sWv[1024];
    int t = threadIdx.x;
    for (int i = t; i < 1024; i += 256) {
        sW2[i] = w_pos2[i];
        sWq[i] = w_q[i];
        sWk[i] = w_k[i];
        sWv[i] = w_v[i];
    }
    int lane = t & 31;
    int g = t >> 5;
    float w1c0 = w_pos1[lane], w1c1 = w_pos1[32 + lane], w1c2 = w_pos1[64 + lane];
    float b1c = b_pos1[lane], b2c = b_pos2[lane];
    __syncthreads();
#pragma unroll 1
    for (int p = blockIdx.x * 8 + g; p < NP; p += gridDim.x * 8) {
        asm volatile("" ::: "memory");   // keep LDS weight reads inside the loop
        float x0 = xyz[(size_t)p * 3 + 0];
        float x1 = xyz[(size_t)p * 3 + 1];
        float x2 = xyz[(size_t)p * 3 + 2];
        float h = fmaxf(x0 * w1c0 + x1 * w1c1 + x2 * w1c2 + b1c, 0.f);
        float P = b2c;
#pragma unroll 8
        for (int j = 0; j < 32; ++j) P += __shfl(h, j, 32) * sW2[j * 32 + lane];
        float xv = xt[(size_t)p * 32 + lane];
        float qin = xv + P;
        float s = xv * xv;
#pragma unroll
        for (int m = 16; m >= 1; m >>= 1) s += __shfl_xor(s, m, 32);
        if (lane == 0) xx[p] = s;
        float qa = 0.f, ka = 0.f, va = 0.f;
#pragma unroll 8
        for (int j = 0; j < 32; ++j) {
            float qj = __shfl(qin, j, 32);
            qa += qj * sWq[j * 32 + lane];
            ka += qj * sWk[j * 32 + lane];
            va += qj * sWv[j * 32 + lane];
        }
        Qf[(size_t)p * 32 + lane] = elu1(qa);
        Kf[(size_t)p * 32 + lane] = elu1(ka);
        Vn[(size_t)p * 32 + lane] = va;   // raw V ((V/k)*k cancels exactly, pow2)
    }
}

// ---------------- K3: KNN — quantized single-pass histogram select ----------------
// Block: 256 threads (4 waves), 4 rows; wave w selects row w.
// Score layout (swizzled): col j = L*64+o stored at sc[r][L*64 + (o ^ (L&31))]
// so lane L owns cols [L*64, L*64+64) and reads are 2-way bank-free.
// All big per-lane state lives in LDS; passes re-read + recompute (no spills).
__global__ __launch_bounds__(256, 2) void k_knn(const float* __restrict__ feat,
                                                const float* __restrict__ xt,
                                                const float* __restrict__ xx,
                                                unsigned* __restrict__ idxg) {
    __shared__ float sc[4][4096];      // 64 KB
    __shared__ float qL[4][32];        // query rows (broadcast reads)
    __shared__ unsigned Hh[4][576];    // 1024 u16 buckets packed + 1/8 pad, per wave
    __shared__ unsigned Oo[4][32];
    int bid = blockIdx.x;
    int b = bid & 7;                   // XCD-swizzle: XCD k keeps batch k in its L2
    int n0 = (bid >> 3) << 2;
    int t = threadIdx.x;

    if (t < 128) {
        int r = t >> 5, c = t & 31;
        qL[r][c] = xt[((size_t)b * NN + n0 + r) * 32 + c];
    }
    float xxr[4];
#pragma unroll
    for (int r = 0; r < 4; ++r) xxr[r] = xx[b * NN + n0 + r];
    const float* fb = feat + (size_t)b * 32 * NN;
    const float* xxb = xx + (size_t)b * NN;
    __syncthreads();

    // ---- distance compute: 4 rows x 4096 cols ----
#pragma unroll 1
    for (int tile = 0; tile < 16; ++tile) {
        asm volatile("" ::: "memory");   // pin qL reads inside the loop (no LICM)
        int j = tile * 256 + t;
        float f[32];
#pragma unroll
        for (int c = 0; c < 32; ++c) f[c] = fb[(size_t)c * NN + j];
        float a0 = 0.f, a1 = 0.f, a2 = 0.f, a3 = 0.f;
#pragma unroll
        for (int cg = 0; cg < 8; ++cg) {
            float4 q0 = *(const float4*)&qL[0][cg * 4];
            float4 q1 = *(const float4*)&qL[1][cg * 4];
            float4 q2 = *(const float4*)&qL[2][cg * 4];
            float4 q3 = *(const float4*)&qL[3][cg * 4];
            float f0 = f[4 * cg], f1 = f[4 * cg + 1], f2 = f[4 * cg + 2], f3 = f[4 * cg + 3];
            a0 += q0.x * f0 + q0.y * f1 + q0.z * f2 + q0.w * f3;
            a1 += q1.x * f0 + q1.y * f1 + q1.z * f2 + q1.w * f3;
            a2 += q2.x * f0 + q2.y * f1 + q2.z * f2 + q2.w * f3;
            a3 += q3.x * f0 + q3.y * f1 + q3.z * f2 + q3.w * f3;
        }
        float xxj = xxb[j];
        int L = j >> 6, o = j & 63;
        int ad = L * 64 + (o ^ (L & 31));
        sc[0][ad] = 2.f * a0 - xxr[0] - xxj;
        sc[1][ad] = 2.f * a1 - xxr[1] - xxj;
        sc[2][ad] = 2.f * a2 - xxr[2] - xxj;
        sc[3][ad] = 2.f * a3 - xxr[3] - xxj;
    }
    __syncthreads();

    // ---- selection: wave w handles row w (all state wave-private) ----
    int w = t >> 6, lane = t & 63;
    float* srow = sc[w];
    unsigned* Hb = Hh[w];
    unsigned* Ob = Oo[w];
    int cxor = lane & 31;
    int abase = lane * 64;

    // pass A: min/max (re-read LDS, nothing cached)
    float mn = INFINITY, mx = -INFINITY;
#pragma unroll 8
    for (int o = 0; o < 64; ++o) {
        float v = srow[abase + (o ^ cxor)];
        mn = fminf(mn, v); mx = fmaxf(mx, v);
    }
#pragma unroll
    for (int off = 32; off >= 1; off >>= 1) {
        mn = fminf(mn, __shfl_xor(mn, off, 64));
        mx = fmaxf(mx, __shfl_xor(mx, off, 64));
    }
    float range = mx - mn;
    float scale = (range > 1e-20f) ? (1021.0f / range) : 0.f;

    // zero per-wave histogram (576 = 64*9 words)
#pragma unroll
    for (int i = 0; i < 9; ++i) Hb[lane + 64 * i] = 0u;
    __syncthreads();

    // pass B: histogram (recompute buckets on the fly)
#pragma unroll 8
    for (int o = 0; o < 64; ++o) {
        float v = srow[abase + (o ^ cxor)];
        int q = (int)((v - mn) * scale);
        q = q < 0 ? 0 : (q > 1023 ? 1023 : q);
        unsigned wd = (unsigned)q >> 1;
        atomicAdd(&Hb[wd + (wd >> 3)], 1u << ((q & 1) * 16));
    }
    __syncthreads();

    // suffix scan: lane L owns buckets [L*16, L*16+16)
    unsigned cvals[16];
#pragma unroll
    for (int i2 = 0; i2 < 8; ++i2) {
        unsigned wdv = Hb[lane * 9 + i2];
        cvals[2 * i2]     = wdv & 0xffffu;
        cvals[2 * i2 + 1] = wdv >> 16;
    }
    unsigned ssum = 0;
#pragma unroll
    for (int i = 0; i < 16; ++i) ssum += cvals[i];
    unsigned acc = ssum;
#pragma unroll
    for (int off = 1; off < 64; off <<= 1) {
        unsigned vv = __shfl_down(acc, off, 64);
        if (lane + off < 64) acc += vv;
    }
    unsigned S_above = acc - ssum;   // count in buckets owned by higher lanes
    int Tl = -1; unsigned basel = 0; unsigned running = S_above;
#pragma unroll
    for (int i = 15; i >= 0; --i) {
        unsigned c = cvals[i];
        unsigned nr = running + c;
        if (Tl < 0 && running < 32u && nr >= 32u) { Tl = lane * 16 + i; basel = running; }
        running = nr;
    }
    unsigned long long bal = __ballot(Tl >= 0);
    int src = __ffsll(bal) - 1;
    int T = __shfl(Tl, src, 64);
    unsigned base = (unsigned)__shfl((int)basel, src, 64);

    // pass C: emit certainly-in (q > T) via ballot compaction; build boundary mask
    unsigned cnt_run = 0;
    unsigned long long mask = 0ull;
#pragma unroll 8
    for (int o = 0; o < 64; ++o) {
        float v = srow[abase + (o ^ cxor)];
        int q = (int)((v - mn) * scale);
        q = q < 0 ? 0 : (q > 1023 ? 1023 : q);
        bool pin = (q > T);
        unsigned long long bm = __ballot(pin);
        if (pin) {
            unsigned pos = cnt_run + (unsigned)__popcll(bm & ((1ull << lane) - 1ull));
            Ob[pos] = (unsigned)(abase + o);
        }
        cnt_run += (unsigned)__popcll(bm);
        if (q == T) mask |= (1ull << o);
    }

    // boundary bucket: exact (value desc, index asc) extraction of remaining
    int need = 32 - (int)base;
    while (need > 0) {
        float bv = -INFINITY; int bj = 1 << 30;
        unsigned long long m2 = mask;
        while (m2) {
            int o = (int)__ffsll(m2) - 1;
            m2 &= m2 - 1ull;
            float vv = srow[abase + (o ^ cxor)];
            if (vv > bv) { bv = vv; bj = abase + o; }
        }
#pragma unroll
        for (int off = 1; off < 64; off <<= 1) {
            float ov = __shfl_xor(bv, off, 64);
            int oj = __shfl_xor(bj, off, 64);
            if (ov > bv || (ov == bv && oj < bj)) { bv = ov; bj = oj; }
        }
        if ((bj >> 6) == lane) mask &= ~(1ull << (bj & 63));
        if (lane == 0) Ob[32 - need] = (unsigned)bj;
        --need;
    }
    __syncthreads();
    if (lane < 32) idxg[((size_t)b * NN + n0 + w) * 32 + lane] = Ob[lane];
}

// ---------------- K4: attention + merge + LN + MLP + LN + residual ----------------
__global__ __launch_bounds__(256, 2) void k_attn(
        const float* __restrict__ xt,
        const float* __restrict__ Qf, const float* __restrict__ Kf,
        const float* __restrict__ Vn, const unsigned* __restrict__ idxg,
        const float* __restrict__ w_merge,
        const float* __restrict__ ln1_g, const float* __restrict__ ln1_b,
        const float* __restrict__ w_mlp1, const float* __restrict__ w_mlp2,
        const float* __restrict__ ln2_g, const float* __restrict__ ln2_b,
        float* __restrict__ out) {
    __shared__ float wmL[32][32];
    __shared__ float w1L[64][64];
    __shared__ float w2L[64][32];
    __shared__ float otile[32][33];
    int t = threadIdx.x;
    for (int i = t; i < 1024; i += 256) wmL[i >> 5][i & 31] = w_merge[i];
    for (int i = t; i < 4096; i += 256) w1L[i >> 6][i & 63] = w_mlp1[i];
    for (int i = t; i < 2048; i += 256) w2L[i >> 5][i & 31] = w_mlp2[i];
    int lane = t & 31, g = t >> 5;
    float l1g = ln1_g[lane], l1b = ln1_b[lane];
    float l2g = ln2_g[lane], l2b = ln2_b[lane];
    __syncthreads();
    int p0 = blockIdx.x * 32;
    int b = p0 / NN;
    size_t bbase = (size_t)b * NN;
    for (int i = 0; i < 4; ++i) {
        int p = p0 + i * 8 + g;
        size_t pb = (size_t)p * 32;
        float q = Qf[pb + lane];
        float x = xt[pb + lane];
        float zacc = 0.f, macc = 0.f;
        for (int k = 0; k < 32; ++k) {
            int j = (int)idxg[pb + k];
            size_t jb = (bbase + (size_t)j) * 32;
            float kf = Kf[jb + lane];
            float vn = Vn[jb + lane];
            float s = q * kf;
            s += __shfl_xor(s, 1, 8);
            s += __shfl_xor(s, 2, 8);
            s += __shfl_xor(s, 4, 8);
            zacc += s;
            macc += s * vn;
        }
        float Z = 1.f / (zacc + 1e-6f);
        float msg = macc * Z;
        float mo = 0.f;
#pragma unroll
        for (int c = 0; c < 32; ++c) mo += __shfl(msg, c, 32) * wmL[c][lane];
        float mean = mo;
#pragma unroll
        for (int m = 16; m >= 1; m >>= 1) mean += __shfl_xor(mean, m, 32);
        mean *= (1.f / 32.f);
        float d = mo - mean;
        float var = d * d;
#pragma unroll
        for (int m = 16; m >= 1; m >>= 1) var += __shfl_xor(var, m, 32);
        var *= (1.f / 32.f);
        float msgn = l1g * d * rsqrtf(var + 1e-5f) + l1b;
        float h0 = 0.f, h1 = 0.f;
#pragma unroll
        for (int c = 0; c < 32; ++c) {
            float xc = __shfl(x, c, 32);
            float mc = __shfl(msgn, c, 32);
            h0 += xc * w1L[c][lane]      + mc * w1L[c + 32][lane];
            h1 += xc * w1L[c][lane + 32] + mc * w1L[c + 32][lane + 32];
        }
        h0 = fmaxf(h0, 0.f); h1 = fmaxf(h1, 0.f);
        float o = 0.f;
#pragma unroll
        for (int c = 0; c < 32; ++c) {
            o += __shfl(h0, c, 32) * w2L[c][lane] + __shfl(h1, c, 32) * w2L[c + 32][lane];
        }
        float mean2 = o;
#pragma unroll
        for (int m = 16; m >= 1; m >>= 1) mean2 += __shfl_xor(mean2, m, 32);
        mean2 *= (1.f / 32.f);
        float d2 = o - mean2;
        float var2 = d2 * d2;
#pragma unroll
        for (int m = 16; m >= 1; m >>= 1) var2 += __shfl_xor(var2, m, 32);
        var2 *= (1.f / 32.f);
        float on = l2g * d2 * rsqrtf(var2 + 1e-5f) + l2b;
        otile[lane][i * 8 + g] = x + on;
    }
    __syncthreads();
    int nn = t & 31, cr = t >> 5;
    int nb = p0 % NN;
#pragma unroll
    for (int r = 0; r < 4; ++r) {
        int c = r * 8 + cr;
        out[((size_t)b * 32 + c) * NN + nb + nn] = otile[c][nn];
    }
}

extern "C" void kernel_launch(void* const* d_in, const int* in_sizes, int n_in,
                              void* d_out, int out_size, void* d_ws, size_t ws_size,
                              hipStream_t stream) {
    const float* feat   = (const float*)d_in[0];
    const float* xyz    = (const float*)d_in[1];
    const float* w_pos1 = (const float*)d_in[2];
    const float* b_pos1 = (const float*)d_in[3];
    const float* w_pos2 = (const float*)d_in[4];
    const float* b_pos2 = (const float*)d_in[5];
    const float* w_q    = (const float*)d_in[6];
    const float* w_k    = (const float*)d_in[7];
    const float* w_v    = (const float*)d_in[8];
    const float* w_mg   = (const float*)d_in[9];
    const float* ln1_g  = (const float*)d_in[10];
    const float* ln1_b  = (const float*)d_in[11];
    const float* w_mlp1 = (const float*)d_in[12];
    const float* w_mlp2 = (const float*)d_in[13];
    const float* ln2_g  = (const float*)d_in[14];
    const float* ln2_b  = (const float*)d_in[15];
    float* ws = (float*)d_ws;
    float* xt = ws + OFF_XT;
    float* Qf = ws + OFF_QF;
    float* Kf = ws + OFF_KF;
    float* Vn = ws + OFF_VN;
    float* xx = ws + OFF_XX;
    unsigned* idxg = (unsigned*)(ws + OFF_IDX);
    float* out = (float*)d_out;

    k_transpose<<<dim3(64, 8), 256, 0, stream>>>(feat, xt);
    k_prep<<<1024, 256, 0, stream>>>(xt, xyz, w_pos1, b_pos1, w_pos2, b_pos2,
                                     w_q, w_k, w_v, Qf, Kf, Vn, xx);
    k_knn<<<8192, 256, 0, stream>>>(feat, xt, xx, idxg);
    k_attn<<<1024, 256, 0, stream>>>(xt, Qf, Kf, Vn, idxg, w_mg, ln1_g, ln1_b,
                                     w_mlp1, w_mlp2, ln2_g, ln2_b, out);
}

// Round 4
// 400.624 us; speedup vs baseline: 5.4598x; 1.7285x over previous
//
#include <hip/hip_runtime.h>
#include <math.h>

#define BB 8
#define CC 32
#define NN 4096
#define KNN 32
#define NP (BB*NN)   // 32768

// workspace float offsets
#define OFF_XT  0u
#define OFF_QF  1048576u
#define OFF_KF  2097152u
#define OFF_VN  3145728u
#define OFF_XX  4194304u
#define OFF_IDX 4227072u   // 1M u32
#define OFF_XH  5275648u   // 1M _Float16 = 512K floats
#define OFF_XL  5799936u   // 1M _Float16

typedef _Float16 f16x8 __attribute__((ext_vector_type(8)));
typedef float f32x4 __attribute__((ext_vector_type(4)));
#define MFMA16(A,B,C) __builtin_amdgcn_mfma_f32_16x16x32_f16(A,B,C,0,0,0)

__device__ __forceinline__ float elu1(float x) {
    return x > 0.f ? x + 1.f : expf(x);
}

// ---------------- K1: transpose feat[B,C,N] -> xt[B,N,C] ----------------
__global__ __launch_bounds__(256) void k_transpose(const float* __restrict__ feat,
                                                   float* __restrict__ xt) {
    __shared__ float tile[32][65];
    int b = blockIdx.y;
    int n0 = blockIdx.x * 64;
    int t = threadIdx.x;
    int nn = t & 63, cr = t >> 6;
#pragma unroll
    for (int r = 0; r < 8; ++r) {
        int c = r * 4 + cr;
        tile[c][nn] = feat[((size_t)b * 32 + c) * NN + n0 + nn];
    }
    __syncthreads();
    int c2 = t & 31, nr = t >> 5;
#pragma unroll
    for (int r = 0; r < 8; ++r) {
        int nl = r * 8 + nr;
        xt[((size_t)b * NN + n0 + nl) * 32 + c2] = tile[c2][nl];
    }
}

// ---------------- K2: per-point prep (weights in LDS — no spills) ----------------
__global__ __launch_bounds__(256, 2) void k_prep(
        const float* __restrict__ xt, const float* __restrict__ xyz,
        const float* __restrict__ w_pos1, const float* __restrict__ b_pos1,
        const float* __restrict__ w_pos2, const float* __restrict__ b_pos2,
        const float* __restrict__ w_q, const float* __restrict__ w_k,
        const float* __restrict__ w_v,
        float* __restrict__ Qf, float* __restrict__ Kf, float* __restrict__ Vn,
        float* __restrict__ xx, _Float16* __restrict__ Xh, _Float16* __restrict__ Xl) {
    __shared__ float sW2[1024], sWq[1024], sWk[1024], sWv[1024];
    int t = threadIdx.x;
    for (int i = t; i < 1024; i += 256) {
        sW2[i] = w_pos2[i];
        sWq[i] = w_q[i];
        sWk[i] = w_k[i];
        sWv[i] = w_v[i];
    }
    int lane = t & 31;
    int g = t >> 5;
    float w1c0 = w_pos1[lane], w1c1 = w_pos1[32 + lane], w1c2 = w_pos1[64 + lane];
    float b1c = b_pos1[lane], b2c = b_pos2[lane];
    __syncthreads();
#pragma unroll 1
    for (int p = blockIdx.x * 8 + g; p < NP; p += gridDim.x * 8) {
        asm volatile("" ::: "memory");   // keep LDS weight reads inside the loop
        float x0 = xyz[(size_t)p * 3 + 0];
        float x1 = xyz[(size_t)p * 3 + 1];
        float x2 = xyz[(size_t)p * 3 + 2];
        float h = fmaxf(x0 * w1c0 + x1 * w1c1 + x2 * w1c2 + b1c, 0.f);
        float P = b2c;
#pragma unroll 8
        for (int j = 0; j < 32; ++j) P += __shfl(h, j, 32) * sW2[j * 32 + lane];
        float xv = xt[(size_t)p * 32 + lane];
        // fp16 hi/lo split for MFMA knn
        _Float16 hv = (_Float16)xv;
        _Float16 lv = (_Float16)(xv - (float)hv);
        Xh[(size_t)p * 32 + lane] = hv;
        Xl[(size_t)p * 32 + lane] = lv;
        float qin = xv + P;
        float s = xv * xv;
#pragma unroll
        for (int m = 16; m >= 1; m >>= 1) s += __shfl_xor(s, m, 32);
        if (lane == 0) xx[p] = s;
        float qa = 0.f, ka = 0.f, va = 0.f;
#pragma unroll 8
        for (int j = 0; j < 32; ++j) {
            float qj = __shfl(qin, j, 32);
            qa += qj * sWq[j * 32 + lane];
            ka += qj * sWk[j * 32 + lane];
            va += qj * sWv[j * 32 + lane];
        }
        Qf[(size_t)p * 32 + lane] = elu1(qa);
        Kf[(size_t)p * 32 + lane] = elu1(ka);
        Vn[(size_t)p * 32 + lane] = va;   // raw V ((V/k)*k cancels exactly, pow2)
    }
}

// ---------------- K3: KNN via MFMA + per-row histogram select ----------------
// Block: 256 threads (4 waves), 32 rows x 4096 cols. Wave w covers cols [w*1024, +1024).
// fp16 hi/lo 4-term MFMA gives scores ~3e-5 accurate; 2 register sweeps
// (hist, emit), exact fp32 tie resolution at the threshold bucket.
__global__ __launch_bounds__(256, 4) void k_knn(
        const _Float16* __restrict__ Xh, const _Float16* __restrict__ Xl,
        const float* __restrict__ xt, const float* __restrict__ xx,
        unsigned* __restrict__ idxg) {
    __shared__ unsigned hist[32 * 144];     // 256 u16 buckets/row, packed + pad/8
    __shared__ unsigned outIdx[32][32];
    __shared__ unsigned tieIdx[32][128];
    __shared__ int sT[32];
    __shared__ unsigned sBase[32];
    __shared__ unsigned outCnt[32], tieCnt[32];
    __shared__ float sM2;
    __shared__ float redbuf[4];

    int bid = blockIdx.x;
    int b = bid & 7;                 // XCD swizzle: batch per XCD
    int n0 = (bid >> 3) << 5;        // 32 rows per block
    int t = threadIdx.x;
    int lane = t & 63, wv = t >> 6;
    size_t bbase = (size_t)b * NN;

    for (int i = t; i < 32 * 144; i += 256) hist[i] = 0;
    if (t < 32) { outCnt[t] = 0; tieCnt[t] = 0; }

    // batch max of xx for conservative quantization bounds
    float lm = 0.f;
    for (int i = t; i < NN; i += 256) lm = fmaxf(lm, xx[bbase + i]);
#pragma unroll
    for (int off = 32; off >= 1; off >>= 1) lm = fmaxf(lm, __shfl_xor(lm, off, 64));
    if (lane == 0) redbuf[wv] = lm;
    __syncthreads();
    if (t == 0) sM2 = fmaxf(fmaxf(redbuf[0], redbuf[1]), fmaxf(redbuf[2], redbuf[3]));
    __syncthreads();
    float M2 = sM2;

    // A fragments: lane l -> point n0 + (l&15) (+16 for tile 1), chans (l>>4)*8..+8
    int al = lane & 15;
    int ak = (lane >> 4) * 8;
    const _Float16* Xhb = Xh + bbase * 32;
    const _Float16* Xlb = Xl + bbase * 32;
    f16x8 Ah0 = *(const f16x8*)(Xhb + (size_t)(n0 + al) * 32 + ak);
    f16x8 Al0 = *(const f16x8*)(Xlb + (size_t)(n0 + al) * 32 + ak);
    f16x8 Ah1 = *(const f16x8*)(Xhb + (size_t)(n0 + 16 + al) * 32 + ak);
    f16x8 Al1 = *(const f16x8*)(Xlb + (size_t)(n0 + 16 + al) * 32 + ak);

    // per-lane row constants: rows (l>>4)*4 + r (r=0..3) and +16
    float xxi[8], scl[8], s2[8];
    int rowloc[8], rowhb[8];
#pragma unroll
    for (int g2 = 0; g2 < 2; ++g2) {
        float4 xv4 = *(const float4*)&xx[bbase + n0 + g2 * 16 + (lane >> 4) * 4];
        xxi[g2 * 4 + 0] = xv4.x; xxi[g2 * 4 + 1] = xv4.y;
        xxi[g2 * 4 + 2] = xv4.z; xxi[g2 * 4 + 3] = xv4.w;
    }
#pragma unroll
    for (int r = 0; r < 8; ++r) {
        scl[r] = 255.99f / (2.f * (xxi[r] + M2));   // lo_r = -2(xxi+M2); ofs = 255.99
        s2[r] = 2.f * scl[r];
        rowloc[r] = (r < 4 ? 0 : 16) + (lane >> 4) * 4 + (r & 3);
        rowhb[r] = rowloc[r] * 144;
    }

    // ---- sweep 1: histogram ----
#pragma unroll 1
    for (int tt = 0; tt < 64; ++tt) {
        int cp = wv * 1024 + tt * 16 + al;
        f16x8 Bh = *(const f16x8*)(Xhb + (size_t)cp * 32 + ak);
        f16x8 Bl = *(const f16x8*)(Xlb + (size_t)cp * 32 + ak);
        f32x4 z = {0.f, 0.f, 0.f, 0.f};
        f32x4 a0 = MFMA16(Al0, Bl, z);
        a0 = MFMA16(Ah0, Bl, a0); a0 = MFMA16(Al0, Bh, a0); a0 = MFMA16(Ah0, Bh, a0);
        f32x4 a1 = MFMA16(Al1, Bl, z);
        a1 = MFMA16(Ah1, Bl, a1); a1 = MFMA16(Al1, Bh, a1); a1 = MFMA16(Ah1, Bh, a1);
        float xxj = xx[bbase + cp];
#pragma unroll
        for (int r = 0; r < 8; ++r) {
            float a = (r < 4) ? a0[r] : a1[r - 4];
            float basef = __builtin_fmaf(-(xxi[r] + xxj), scl[r], 255.99f);
            float qf = __builtin_fmaf(a, s2[r], basef);
            int qi = (int)qf;
            qi = qi < 0 ? 0 : (qi > 255 ? 255 : qi);
            unsigned wd = (unsigned)qi >> 1;
            atomicAdd(&hist[rowhb[r] + wd + (wd >> 3)], 1u << ((qi & 1) * 16));
        }
    }
    __syncthreads();

    // ---- scan: per row suffix over 256 buckets -> T, base ----
#pragma unroll 1
    for (int rr = 0; rr < 8; ++rr) {
        int row = wv * 8 + rr;
        unsigned* Hr = &hist[row * 144];
        int w0i = 2 * lane, w1i = 2 * lane + 1;
        unsigned wa = Hr[w0i + (w0i >> 3)];
        unsigned wb = Hr[w1i + (w1i >> 3)];
        unsigned c0 = wa & 0xffffu, c1 = wa >> 16, c2 = wb & 0xffffu, c3 = wb >> 16;
        unsigned ss = c0 + c1 + c2 + c3;
        unsigned acc = ss;
#pragma unroll
        for (int off = 1; off < 64; off <<= 1) {
            unsigned vv = __shfl_down(acc, off, 64);
            if (lane + off < 64) acc += vv;
        }
        unsigned run = acc - ss;   // strictly above this lane's buckets
        int Tl = -1; unsigned bl = 0;
        if (run < 32u && run + c3 >= 32u) { Tl = 4 * lane + 3; bl = run; } run += c3;
        if (Tl < 0 && run < 32u && run + c2 >= 32u) { Tl = 4 * lane + 2; bl = run; } run += c2;
        if (Tl < 0 && run < 32u && run + c1 >= 32u) { Tl = 4 * lane + 1; bl = run; } run += c1;
        if (Tl < 0 && run < 32u && run + c0 >= 32u) { Tl = 4 * lane + 0; bl = run; }
        unsigned long long bal = __ballot(Tl >= 0);
        int src = __ffsll(bal) - 1;
        if (lane == 0) {
            sT[row] = 0; sBase[row] = 0;   // will be overwritten below
        }
        int Tv = __shfl(Tl, src, 64);
        unsigned bv = (unsigned)__shfl((int)bl, src, 64);
        if (lane == 0) { sT[row] = Tv; sBase[row] = bv; }
    }
    __syncthreads();

    int Tr[8];
#pragma unroll
    for (int r = 0; r < 8; ++r) Tr[r] = sT[rowloc[r]];

    // ---- sweep 2: identical recompute, emit certainly-in + ties ----
#pragma unroll 1
    for (int tt = 0; tt < 64; ++tt) {
        int cp = wv * 1024 + tt * 16 + al;
        f16x8 Bh = *(const f16x8*)(Xhb + (size_t)cp * 32 + ak);
        f16x8 Bl = *(const f16x8*)(Xlb + (size_t)cp * 32 + ak);
        f32x4 z = {0.f, 0.f, 0.f, 0.f};
        f32x4 a0 = MFMA16(Al0, Bl, z);
        a0 = MFMA16(Ah0, Bl, a0); a0 = MFMA16(Al0, Bh, a0); a0 = MFMA16(Ah0, Bh, a0);
        f32x4 a1 = MFMA16(Al1, Bl, z);
        a1 = MFMA16(Ah1, Bl, a1); a1 = MFMA16(Al1, Bh, a1); a1 = MFMA16(Ah1, Bh, a1);
        float xxj = xx[bbase + cp];
#pragma unroll
        for (int r = 0; r < 8; ++r) {
            float a = (r < 4) ? a0[r] : a1[r - 4];
            float basef = __builtin_fmaf(-(xxi[r] + xxj), scl[r], 255.99f);
            float qf = __builtin_fmaf(a, s2[r], basef);
            int qi = (int)qf;
            qi = qi < 0 ? 0 : (qi > 255 ? 255 : qi);
            int row = rowloc[r];
            if (qi > Tr[r]) {
                unsigned pos = atomicAdd(&outCnt[row], 1u);
                outIdx[row][pos] = (unsigned)cp;
            } else if (qi == Tr[r]) {
                unsigned tp = atomicAdd(&tieCnt[row], 1u);
                if (tp < 128u) tieIdx[row][tp] = (unsigned)cp;
            }
        }
    }
    __syncthreads();

    // ---- resolve boundary bucket with exact fp32 scores ----
#pragma unroll 1
    for (int rr = 0; rr < 8; ++rr) {
        int row = wv * 8 + rr;
        int gr = n0 + row;
        unsigned bA = sBase[row];
        int need = 32 - (int)bA;
        if (need <= 0) continue;
        int nt = (int)tieCnt[row]; if (nt > 128) nt = 128;
        const float* xr = xt + (bbase + gr) * 32;
        float xxi_r = xx[bbase + gr];
        float v0 = -INFINITY, v1 = -INFINITY;
        int i0 = 0x7fffffff, i1 = 0x7fffffff;
        bool a0v = lane < nt, a1v = lane + 64 < nt;
        if (a0v) {
            int c = (int)tieIdx[row][lane];
            const float* xc = xt + (bbase + c) * 32;
            float dot = 0.f;
#pragma unroll
            for (int ch = 0; ch < 32; ch += 4) {
                float4 rv = *(const float4*)(xr + ch);
                float4 cv = *(const float4*)(xc + ch);
                dot = __builtin_fmaf(rv.x, cv.x, dot);
                dot = __builtin_fmaf(rv.y, cv.y, dot);
                dot = __builtin_fmaf(rv.z, cv.z, dot);
                dot = __builtin_fmaf(rv.w, cv.w, dot);
            }
            v0 = 2.f * dot - xxi_r - xx[bbase + c];
            i0 = c;
        }
        if (a1v) {
            int c = (int)tieIdx[row][lane + 64];
            const float* xc = xt + (bbase + c) * 32;
            float dot = 0.f;
#pragma unroll
            for (int ch = 0; ch < 32; ch += 4) {
                float4 rv = *(const float4*)(xr + ch);
                float4 cv = *(const float4*)(xc + ch);
                dot = __builtin_fmaf(rv.x, cv.x, dot);
                dot = __builtin_fmaf(rv.y, cv.y, dot);
                dot = __builtin_fmaf(rv.z, cv.z, dot);
                dot = __builtin_fmaf(rv.w, cv.w, dot);
            }
            v1 = 2.f * dot - xxi_r - xx[bbase + c];
            i1 = c;
        }
        for (int it = 0; it < need; ++it) {
            float bv = -INFINITY; int bj = 0x7fffffff;
            if (a0v && (v0 > bv || (v0 == bv && i0 < bj))) { bv = v0; bj = i0; }
            if (a1v && (v1 > bv || (v1 == bv && i1 < bj))) { bv = v1; bj = i1; }
#pragma unroll
            for (int off = 1; off < 64; off <<= 1) {
                float ov = __shfl_xor(bv, off, 64);
                int oj = __shfl_xor(bj, off, 64);
                if (ov > bv || (ov == bv && oj < bj)) { bv = ov; bj = oj; }
            }
            if (a0v && i0 == bj) a0v = false;
            if (a1v && i1 == bj) a1v = false;
            if (lane == 0) outIdx[row][bA + it] = (unsigned)bj;
        }
    }
    __syncthreads();

    for (int i = t; i < 1024; i += 256)
        idxg[(bbase + n0 + (i >> 5)) * 32 + (i & 31)] = outIdx[i >> 5][i & 31];
}

// ---------------- K4: attention + merge + LN + MLP + LN + residual ----------------
__global__ __launch_bounds__(256, 2) void k_attn(
        const float* __restrict__ xt,
        const float* __restrict__ Qf, const float* __restrict__ Kf,
        const float* __restrict__ Vn, const unsigned* __restrict__ idxg,
        const float* __restrict__ w_merge,
        const float* __restrict__ ln1_g, const float* __restrict__ ln1_b,
        const float* __restrict__ w_mlp1, const float* __restrict__ w_mlp2,
        const float* __restrict__ ln2_g, const float* __restrict__ ln2_b,
        float* __restrict__ out) {
    __shared__ float wmL[32][32];
    __shared__ float w1L[64][64];
    __shared__ float w2L[64][32];
    __shared__ float otile[32][33];
    int t = threadIdx.x;
    for (int i = t; i < 1024; i += 256) wmL[i >> 5][i & 31] = w_merge[i];
    for (int i = t; i < 4096; i += 256) w1L[i >> 6][i & 63] = w_mlp1[i];
    for (int i = t; i < 2048; i += 256) w2L[i >> 5][i & 31] = w_mlp2[i];
    int lane = t & 31, g = t >> 5;
    float l1g = ln1_g[lane], l1b = ln1_b[lane];
    float l2g = ln2_g[lane], l2b = ln2_b[lane];
    __syncthreads();
    int p0 = blockIdx.x * 32;
    int b = p0 / NN;
    size_t bbase = (size_t)b * NN;
    for (int i = 0; i < 4; ++i) {
        int p = p0 + i * 8 + g;
        size_t pb = (size_t)p * 32;
        float q = Qf[pb + lane];
        float x = xt[pb + lane];
        float zacc = 0.f, macc = 0.f;
        for (int k = 0; k < 32; ++k) {
            int j = (int)idxg[pb + k];
            size_t jb = (bbase + (size_t)j) * 32;
            float kf = Kf[jb + lane];
            float vn = Vn[jb + lane];
            float s = q * kf;
            s += __shfl_xor(s, 1, 8);
            s += __shfl_xor(s, 2, 8);
            s += __shfl_xor(s, 4, 8);
            zacc += s;
            macc += s * vn;
        }
        float Z = 1.f / (zacc + 1e-6f);
        float msg = macc * Z;
        float mo = 0.f;
#pragma unroll
        for (int c = 0; c < 32; ++c) mo += __shfl(msg, c, 32) * wmL[c][lane];
        float mean = mo;
#pragma unroll
        for (int m = 16; m >= 1; m >>= 1) mean += __shfl_xor(mean, m, 32);
        mean *= (1.f / 32.f);
        float d = mo - mean;
        float var = d * d;
#pragma unroll
        for (int m = 16; m >= 1; m >>= 1) var += __shfl_xor(var, m, 32);
        var *= (1.f / 32.f);
        float msgn = l1g * d * rsqrtf(var + 1e-5f) + l1b;
        float h0 = 0.f, h1 = 0.f;
#pragma unroll
        for (int c = 0; c < 32; ++c) {
            float xc = __shfl(x, c, 32);
            float mc = __shfl(msgn, c, 32);
            h0 += xc * w1L[c][lane]      + mc * w1L[c + 32][lane];
            h1 += xc * w1L[c][lane + 32] + mc * w1L[c + 32][lane + 32];
        }
        h0 = fmaxf(h0, 0.f); h1 = fmaxf(h1, 0.f);
        float o = 0.f;
#pragma unroll
        for (int c = 0; c < 32; ++c) {
            o += __shfl(h0, c, 32) * w2L[c][lane] + __shfl(h1, c, 32) * w2L[c + 32][lane];
        }
        float mean2 = o;
#pragma unroll
        for (int m = 16; m >= 1; m >>= 1) mean2 += __shfl_xor(mean2, m, 32);
        mean2 *= (1.f / 32.f);
        float d2 = o - mean2;
        float var2 = d2 * d2;
#pragma unroll
        for (int m = 16; m >= 1; m >>= 1) var2 += __shfl_xor(var2, m, 32);
        var2 *= (1.f / 32.f);
        float on = l2g * d2 * rsqrtf(var2 + 1e-5f) + l2b;
        otile[lane][i * 8 + g] = x + on;
    }
    __syncthreads();
    int nn = t & 31, cr = t >> 5;
    int nb = p0 % NN;
#pragma unroll
    for (int r = 0; r < 4; ++r) {
        int c = r * 8 + cr;
        out[((size_t)b * 32 + c) * NN + nb + nn] = otile[c][nn];
    }
}

extern "C" void kernel_launch(void* const* d_in, const int* in_sizes, int n_in,
                              void* d_out, int out_size, void* d_ws, size_t ws_size,
                              hipStream_t stream) {
    const float* feat   = (const float*)d_in[0];
    const float* xyz    = (const float*)d_in[1];
    const float* w_pos1 = (const float*)d_in[2];
    const float* b_pos1 = (const float*)d_in[3];
    const float* w_pos2 = (const float*)d_in[4];
    const float* b_pos2 = (const float*)d_in[5];
    const float* w_q    = (const float*)d_in[6];
    const float* w_k    = (const float*)d_in[7];
    const float* w_v    = (const float*)d_in[8];
    const float* w_mg   = (const float*)d_in[9];
    const float* ln1_g  = (const float*)d_in[10];
    const float* ln1_b  = (const float*)d_in[11];
    const float* w_mlp1 = (const float*)d_in[12];
    const float* w_mlp2 = (const float*)d_in[13];
    const float* ln2_g  = (const float*)d_in[14];
    const float* ln2_b  = (const float*)d_in[15];
    float* ws = (float*)d_ws;
    float* xt = ws + OFF_XT;
    float* Qf = ws + OFF_QF;
    float* Kf = ws + OFF_KF;
    float* Vn = ws + OFF_VN;
    float* xx = ws + OFF_XX;
    unsigned* idxg = (unsigned*)(ws + OFF_IDX);
    _Float16* Xh = (_Float16*)(ws + OFF_XH);
    _Float16* Xl = (_Float16*)(ws + OFF_XL);
    float* out = (float*)d_out;

    k_transpose<<<dim3(64, 8), 256, 0, stream>>>(feat, xt);
    k_prep<<<1024, 256, 0, stream>>>(xt, xyz, w_pos1, b_pos1, w_pos2, b_pos2,
                                     w_q, w_k, w_v, Qf, Kf, Vn, xx, Xh, Xl);
    k_knn<<<1024, 256, 0, stream>>>(Xh, Xl, xt, xx, idxg);
    k_attn<<<1024, 256, 0, stream>>>(xt, Qf, Kf, Vn, idxg, w_mg, ln1_g, ln1_b,
                                     w_mlp1, w_mlp2, ln2_g, ln2_b, out);
}

// Round 5
// 391.119 us; speedup vs baseline: 5.5925x; 1.0243x over previous
//
#include <hip/hip_runtime.h>
#include <math.h>

#define BB 8
#define CC 32
#define NN 4096
#define KNN 32
#define NP (BB*NN)   // 32768

// workspace float offsets
#define OFF_XT  0u
#define OFF_QF  1048576u
#define OFF_KF  2097152u
#define OFF_VN  3145728u
#define OFF_XX  4194304u
#define OFF_IDX 4227072u   // 1M u32
#define OFF_XH  5275648u   // 1M _Float16 = 512K floats
#define OFF_XL  5799936u   // 1M _Float16

typedef _Float16 f16x8 __attribute__((ext_vector_type(8)));
typedef float f32x4 __attribute__((ext_vector_type(4)));
#define MFMA16(A,B,C) __builtin_amdgcn_mfma_f32_16x16x32_f16(A,B,C,0,0,0)

__device__ __forceinline__ float elu1(float x) {
    return x > 0.f ? x + 1.f : expf(x);
}

// ---------------- K1: transpose feat[B,C,N] -> xt[B,N,C] + Xh/Xl/xx ----------------
__global__ __launch_bounds__(256) void k_transpose(const float* __restrict__ feat,
                                                   float* __restrict__ xt,
                                                   _Float16* __restrict__ Xh,
                                                   _Float16* __restrict__ Xl,
                                                   float* __restrict__ xx) {
    __shared__ float tile[32][65];
    int b = blockIdx.y;
    int n0 = blockIdx.x * 64;
    int t = threadIdx.x;
    int nn = t & 63, cr = t >> 6;
#pragma unroll
    for (int r = 0; r < 8; ++r) {
        int c = r * 4 + cr;
        tile[c][nn] = feat[((size_t)b * 32 + c) * NN + n0 + nn];
    }
    __syncthreads();
    int c2 = t & 31, nr = t >> 5;
#pragma unroll
    for (int r = 0; r < 8; ++r) {
        int nl = r * 8 + nr;
        size_t gi = ((size_t)b * NN + n0 + nl) * 32 + c2;
        float v = tile[c2][nl];
        xt[gi] = v;
        _Float16 hv = (_Float16)v;
        Xh[gi] = hv;
        Xl[gi] = (_Float16)(v - (float)hv);
    }
    if (t < 64) {
        float s = 0.f;
#pragma unroll
        for (int c = 0; c < 32; ++c) { float u = tile[c][t]; s += u * u; }
        xx[(size_t)b * NN + n0 + t] = s;
    }
}

// ---------------- K2: per-point prep (weights in LDS — no spills) ----------------
__global__ __launch_bounds__(256, 2) void k_prep(
        const float* __restrict__ xt, const float* __restrict__ xyz,
        const float* __restrict__ w_pos1, const float* __restrict__ b_pos1,
        const float* __restrict__ w_pos2, const float* __restrict__ b_pos2,
        const float* __restrict__ w_q, const float* __restrict__ w_k,
        const float* __restrict__ w_v,
        float* __restrict__ Qf, float* __restrict__ Kf, float* __restrict__ Vn) {
    __shared__ float sW2[1024], sWq[1024], sWk[1024], sWv[1024];
    int t = threadIdx.x;
    for (int i = t; i < 1024; i += 256) {
        sW2[i] = w_pos2[i];
        sWq[i] = w_q[i];
        sWk[i] = w_k[i];
        sWv[i] = w_v[i];
    }
    int lane = t & 31;
    int g = t >> 5;
    float w1c0 = w_pos1[lane], w1c1 = w_pos1[32 + lane], w1c2 = w_pos1[64 + lane];
    float b1c = b_pos1[lane], b2c = b_pos2[lane];
    __syncthreads();
#pragma unroll 1
    for (int p = blockIdx.x * 8 + g; p < NP; p += gridDim.x * 8) {
        asm volatile("" ::: "memory");   // keep LDS weight reads inside the loop
        float x0 = xyz[(size_t)p * 3 + 0];
        float x1 = xyz[(size_t)p * 3 + 1];
        float x2 = xyz[(size_t)p * 3 + 2];
        float h = fmaxf(x0 * w1c0 + x1 * w1c1 + x2 * w1c2 + b1c, 0.f);
        float P = b2c;
#pragma unroll 8
        for (int j = 0; j < 32; ++j) P += __shfl(h, j, 32) * sW2[j * 32 + lane];
        float xv = xt[(size_t)p * 32 + lane];
        float qin = xv + P;
        float qa = 0.f, ka = 0.f, va = 0.f;
#pragma unroll 8
        for (int j = 0; j < 32; ++j) {
            float qj = __shfl(qin, j, 32);
            qa += qj * sWq[j * 32 + lane];
            ka += qj * sWk[j * 32 + lane];
            va += qj * sWv[j * 32 + lane];
        }
        Qf[(size_t)p * 32 + lane] = elu1(qa);
        Kf[(size_t)p * 32 + lane] = elu1(ka);
        Vn[(size_t)p * 32 + lane] = va;   // raw V ((V/k)*k cancels exactly, pow2)
    }
}

// ---------------- K3: KNN via MFMA + per-row histogram select (pipelined) ----------------
__global__ __launch_bounds__(256, 4) void k_knn(
        const _Float16* __restrict__ Xh, const _Float16* __restrict__ Xl,
        const float* __restrict__ xt, const float* __restrict__ xx,
        unsigned* __restrict__ idxg) {
    __shared__ unsigned hist[32 * 144];     // 256 u16 buckets/row: word=q&127 (+pad/8), half=q>>7
    __shared__ unsigned outIdx[32][32];
    __shared__ unsigned tieIdx[32][128];
    __shared__ int sT[32];
    __shared__ unsigned sBase[32];
    __shared__ unsigned outCnt[32], tieCnt[32];
    __shared__ float sM2;
    __shared__ float redbuf[4];

    int bid = blockIdx.x;
    int b = bid & 7;                 // XCD swizzle: batch per XCD
    int n0 = (bid >> 3) << 5;        // 32 rows per block
    int t = threadIdx.x;
    int lane = t & 63, wv = t >> 6;
    size_t bbase = (size_t)b * NN;

    for (int i = t; i < 32 * 144; i += 256) hist[i] = 0;
    if (t < 32) { outCnt[t] = 0; tieCnt[t] = 0; }

    // batch max of xx for conservative quantization bounds
    float lm = 0.f;
    for (int i = t; i < NN; i += 256) lm = fmaxf(lm, xx[bbase + i]);
#pragma unroll
    for (int off = 32; off >= 1; off >>= 1) lm = fmaxf(lm, __shfl_xor(lm, off, 64));
    if (lane == 0) redbuf[wv] = lm;
    __syncthreads();
    if (t == 0) sM2 = fmaxf(fmaxf(redbuf[0], redbuf[1]), fmaxf(redbuf[2], redbuf[3]));
    __syncthreads();
    float M2 = sM2;

    // A fragments: lane l -> point n0 + (l&15) (+16 for tile 1), chans (l>>4)*8..+8
    int al = lane & 15;
    int ak = (lane >> 4) * 8;
    const _Float16* Xhb = Xh + bbase * 32;
    const _Float16* Xlb = Xl + bbase * 32;
    f16x8 Ah0 = *(const f16x8*)(Xhb + (size_t)(n0 + al) * 32 + ak);
    f16x8 Al0 = *(const f16x8*)(Xlb + (size_t)(n0 + al) * 32 + ak);
    f16x8 Ah1 = *(const f16x8*)(Xhb + (size_t)(n0 + 16 + al) * 32 + ak);
    f16x8 Al1 = *(const f16x8*)(Xlb + (size_t)(n0 + 16 + al) * 32 + ak);

    // per-lane row constants: rows (l>>4)*4 + r (r=0..3) and +16
    float scl[8], s2[8], pr[8];
    int rowloc[8], rowhb[8];
    {
        float xxi[8];
#pragma unroll
        for (int g2 = 0; g2 < 2; ++g2) {
            float4 xv4 = *(const float4*)&xx[bbase + n0 + g2 * 16 + (lane >> 4) * 4];
            xxi[g2 * 4 + 0] = xv4.x; xxi[g2 * 4 + 1] = xv4.y;
            xxi[g2 * 4 + 2] = xv4.z; xxi[g2 * 4 + 3] = xv4.w;
        }
#pragma unroll
        for (int r = 0; r < 8; ++r) {
            scl[r] = 255.99f / (2.f * (xxi[r] + M2));
            s2[r] = 2.f * scl[r];
            pr[r] = __builtin_fmaf(-xxi[r], scl[r], 255.99f);
            rowloc[r] = (r < 4 ? 0 : 16) + (lane >> 4) * 4 + (r & 3);
            rowhb[r] = rowloc[r] * 144;
        }
    }

    int cp0 = wv * 1024 + al;

    // ---- sweep 1: histogram (pipelined) ----
    {
        f16x8 Bh_c = *(const f16x8*)(Xhb + (size_t)cp0 * 32 + ak);
        f16x8 Bl_c = *(const f16x8*)(Xlb + (size_t)cp0 * 32 + ak);
        float xxj_c = xx[bbase + cp0];
#pragma unroll 1
        for (int tt = 0; tt < 64; ++tt) {
            int cpn = cp0 + ((tt + 1) & 63) * 16;
            f16x8 Bh_n = *(const f16x8*)(Xhb + (size_t)cpn * 32 + ak);
            f16x8 Bl_n = *(const f16x8*)(Xlb + (size_t)cpn * 32 + ak);
            float xxj_n = xx[bbase + cpn];
            f32x4 z = {0.f, 0.f, 0.f, 0.f};
            f32x4 u0 = MFMA16(Al0, Bl_c, z);
            f32x4 w0 = MFMA16(Ah0, Bh_c, z);
            f32x4 u1 = MFMA16(Al1, Bl_c, z);
            f32x4 w1 = MFMA16(Ah1, Bh_c, z);
            u0 = MFMA16(Ah0, Bl_c, u0);
            w0 = MFMA16(Al0, Bh_c, w0);
            u1 = MFMA16(Ah1, Bl_c, u1);
            w1 = MFMA16(Al1, Bh_c, w1);
            f32x4 a0 = u0 + w0;
            f32x4 a1 = u1 + w1;
            float bj[8];
#pragma unroll
            for (int r = 0; r < 8; ++r) bj[r] = __builtin_fmaf(-xxj_c, scl[r], pr[r]);
#pragma unroll
            for (int r = 0; r < 8; ++r) {
                float a = (r < 4) ? a0[r] : a1[r - 4];
                float qf = __builtin_fmaf(a, s2[r], bj[r]);
                int qi = (int)fminf(fmaxf(qf, 0.f), 255.f);
                int w = qi & 127;
                atomicAdd(&hist[rowhb[r] + w + (w >> 3)], 1u << ((qi & 128) >> 3));
            }
            Bh_c = Bh_n; Bl_c = Bl_n; xxj_c = xxj_n;
        }
    }
    __syncthreads();

    // ---- scan: per row suffix over 256 buckets -> T, base ----
#pragma unroll 1
    for (int rr = 0; rr < 8; ++rr) {
        int row = wv * 8 + rr;
        unsigned* Hr = &hist[row * 144];
        unsigned cnt[4];
#pragma unroll
        for (int i = 0; i < 4; ++i) {
            int q = 4 * lane + i;
            int w = q & 127;
            cnt[i] = (Hr[w + (w >> 3)] >> ((q & 128) >> 3)) & 0xffffu;
        }
        unsigned ss = cnt[0] + cnt[1] + cnt[2] + cnt[3];
        unsigned acc = ss;
#pragma unroll
        for (int off = 1; off < 64; off <<= 1) {
            unsigned vv = __shfl_down(acc, off, 64);
            if (lane + off < 64) acc += vv;
        }
        unsigned run = acc - ss;   // strictly above this lane's buckets
        int Tl = -1; unsigned bl = 0;
        if (run < 32u && run + cnt[3] >= 32u) { Tl = 4 * lane + 3; bl = run; } run += cnt[3];
        if (Tl < 0 && run < 32u && run + cnt[2] >= 32u) { Tl = 4 * lane + 2; bl = run; } run += cnt[2];
        if (Tl < 0 && run < 32u && run + cnt[1] >= 32u) { Tl = 4 * lane + 1; bl = run; } run += cnt[1];
        if (Tl < 0 && run < 32u && run + cnt[0] >= 32u) { Tl = 4 * lane + 0; bl = run; }
        unsigned long long bal = __ballot(Tl >= 0);
        int src = __ffsll(bal) - 1;
        int Tv = __shfl(Tl, src, 64);
        unsigned bv = (unsigned)__shfl((int)bl, src, 64);
        if (lane == 0) { sT[row] = Tv; sBase[row] = bv; }
    }
    __syncthreads();

    int Tr[8];
#pragma unroll
    for (int r = 0; r < 8; ++r) Tr[r] = sT[rowloc[r]];

    // ---- sweep 2: identical recompute, emit certainly-in + ties (pipelined) ----
    {
        f16x8 Bh_c = *(const f16x8*)(Xhb + (size_t)cp0 * 32 + ak);
        f16x8 Bl_c = *(const f16x8*)(Xlb + (size_t)cp0 * 32 + ak);
        float xxj_c = xx[bbase + cp0];
#pragma unroll 1
        for (int tt = 0; tt < 64; ++tt) {
            int cp = cp0 + tt * 16;
            int cpn = cp0 + ((tt + 1) & 63) * 16;
            f16x8 Bh_n = *(const f16x8*)(Xhb + (size_t)cpn * 32 + ak);
            f16x8 Bl_n = *(const f16x8*)(Xlb + (size_t)cpn * 32 + ak);
            float xxj_n = xx[bbase + cpn];
            f32x4 z = {0.f, 0.f, 0.f, 0.f};
            f32x4 u0 = MFMA16(Al0, Bl_c, z);
            f32x4 w0 = MFMA16(Ah0, Bh_c, z);
            f32x4 u1 = MFMA16(Al1, Bl_c, z);
            f32x4 w1 = MFMA16(Ah1, Bh_c, z);
            u0 = MFMA16(Ah0, Bl_c, u0);
            w0 = MFMA16(Al0, Bh_c, w0);
            u1 = MFMA16(Ah1, Bl_c, u1);
            w1 = MFMA16(Al1, Bh_c, w1);
            f32x4 a0 = u0 + w0;
            f32x4 a1 = u1 + w1;
            float bj[8];
#pragma unroll
            for (int r = 0; r < 8; ++r) bj[r] = __builtin_fmaf(-xxj_c, scl[r], pr[r]);
#pragma unroll
            for (int r = 0; r < 8; ++r) {
                float a = (r < 4) ? a0[r] : a1[r - 4];
                float qf = __builtin_fmaf(a, s2[r], bj[r]);
                int qi = (int)fminf(fmaxf(qf, 0.f), 255.f);
                int row = rowloc[r];
                if (qi > Tr[r]) {
                    unsigned pos = atomicAdd(&outCnt[row], 1u);
                    outIdx[row][pos] = (unsigned)cp;
                } else if (qi == Tr[r]) {
                    unsigned tp = atomicAdd(&tieCnt[row], 1u);
                    if (tp < 128u) tieIdx[row][tp] = (unsigned)cp;
                }
            }
            Bh_c = Bh_n; Bl_c = Bl_n; xxj_c = xxj_n;
        }
    }
    __syncthreads();

    // ---- resolve boundary bucket with exact fp32 scores ----
#pragma unroll 1
    for (int rr = 0; rr < 8; ++rr) {
        int row = wv * 8 + rr;
        int gr = n0 + row;
        unsigned bA = sBase[row];
        int need = 32 - (int)bA;
        if (need <= 0) continue;
        int nt = (int)tieCnt[row]; if (nt > 128) nt = 128;
        const float* xr = xt + (bbase + gr) * 32;
        float xxi_r = xx[bbase + gr];
        float v0 = -INFINITY, v1 = -INFINITY;
        int i0 = 0x7fffffff, i1 = 0x7fffffff;
        bool a0v = lane < nt, a1v = lane + 64 < nt;
        if (a0v) {
            int c = (int)tieIdx[row][lane];
            const float* xc = xt + (bbase + c) * 32;
            float dot = 0.f;
#pragma unroll
            for (int ch = 0; ch < 32; ch += 4) {
                float4 rv = *(const float4*)(xr + ch);
                float4 cv = *(const float4*)(xc + ch);
                dot = __builtin_fmaf(rv.x, cv.x, dot);
                dot = __builtin_fmaf(rv.y, cv.y, dot);
                dot = __builtin_fmaf(rv.z, cv.z, dot);
                dot = __builtin_fmaf(rv.w, cv.w, dot);
            }
            v0 = 2.f * dot - xxi_r - xx[bbase + c];
            i0 = c;
        }
        if (a1v) {
            int c = (int)tieIdx[row][lane + 64];
            const float* xc = xt + (bbase + c) * 32;
            float dot = 0.f;
#pragma unroll
            for (int ch = 0; ch < 32; ch += 4) {
                float4 rv = *(const float4*)(xr + ch);
                float4 cv = *(const float4*)(xc + ch);
                dot = __builtin_fmaf(rv.x, cv.x, dot);
                dot = __builtin_fmaf(rv.y, cv.y, dot);
                dot = __builtin_fmaf(rv.z, cv.z, dot);
                dot = __builtin_fmaf(rv.w, cv.w, dot);
            }
            v1 = 2.f * dot - xxi_r - xx[bbase + c];
            i1 = c;
        }
        for (int it = 0; it < need; ++it) {
            float bvv = -INFINITY; int bj2 = 0x7fffffff;
            if (a0v && (v0 > bvv || (v0 == bvv && i0 < bj2))) { bvv = v0; bj2 = i0; }
            if (a1v && (v1 > bvv || (v1 == bvv && i1 < bj2))) { bvv = v1; bj2 = i1; }
#pragma unroll
            for (int off = 1; off < 64; off <<= 1) {
                float ov = __shfl_xor(bvv, off, 64);
                int oj = __shfl_xor(bj2, off, 64);
                if (ov > bvv || (ov == bvv && oj < bj2)) { bvv = ov; bj2 = oj; }
            }
            if (a0v && i0 == bj2) a0v = false;
            if (a1v && i1 == bj2) a1v = false;
            if (lane == 0) outIdx[row][bA + it] = (unsigned)bj2;
        }
    }
    __syncthreads();

    for (int i = t; i < 1024; i += 256)
        idxg[(bbase + n0 + (i >> 5)) * 32 + (i & 31)] = outIdx[i >> 5][i & 31];
}

// ---------------- K4: attention + merge + LN + MLP + LN + residual ----------------
__global__ __launch_bounds__(256, 2) void k_attn(
        const float* __restrict__ xt,
        const float* __restrict__ Qf, const float* __restrict__ Kf,
        const float* __restrict__ Vn, const unsigned* __restrict__ idxg,
        const float* __restrict__ w_merge,
        const float* __restrict__ ln1_g, const float* __restrict__ ln1_b,
        const float* __restrict__ w_mlp1, const float* __restrict__ w_mlp2,
        const float* __restrict__ ln2_g, const float* __restrict__ ln2_b,
        float* __restrict__ out) {
    __shared__ float wmL[32][32];
    __shared__ float w1L[64][64];
    __shared__ float w2L[64][32];
    __shared__ float otile[32][33];
    int t = threadIdx.x;
    for (int i = t; i < 1024; i += 256) wmL[i >> 5][i & 31] = w_merge[i];
    for (int i = t; i < 4096; i += 256) w1L[i >> 6][i & 63] = w_mlp1[i];
    for (int i = t; i < 2048; i += 256) w2L[i >> 5][i & 31] = w_mlp2[i];
    int lane = t & 31, g = t >> 5;
    float l1g = ln1_g[lane], l1b = ln1_b[lane];
    float l2g = ln2_g[lane], l2b = ln2_b[lane];
    __syncthreads();
    int p0 = blockIdx.x * 32;
    int b = p0 / NN;
    size_t bbase = (size_t)b * NN;
    for (int i = 0; i < 4; ++i) {
        int p = p0 + i * 8 + g;
        size_t pb = (size_t)p * 32;
        float q = Qf[pb + lane];
        float x = xt[pb + lane];
        int jv = (int)idxg[pb + lane];     // lane k holds neighbor index k
        float zacc = 0.f, macc = 0.f;
#pragma unroll
        for (int k = 0; k < 32; k += 4) {
            int j0 = __shfl(jv, k, 32);
            int j1 = __shfl(jv, k + 1, 32);
            int j2 = __shfl(jv, k + 2, 32);
            int j3 = __shfl(jv, k + 3, 32);
            size_t o0 = (bbase + (size_t)j0) * 32 + lane;
            size_t o1 = (bbase + (size_t)j1) * 32 + lane;
            size_t o2 = (bbase + (size_t)j2) * 32 + lane;
            size_t o3 = (bbase + (size_t)j3) * 32 + lane;
            float kf0 = Kf[o0], kf1 = Kf[o1], kf2 = Kf[o2], kf3 = Kf[o3];
            float vn0 = Vn[o0], vn1 = Vn[o1], vn2 = Vn[o2], vn3 = Vn[o3];
            float s0 = q * kf0, s1 = q * kf1, s2 = q * kf2, s3 = q * kf3;
            s0 += __shfl_xor(s0, 1, 8); s1 += __shfl_xor(s1, 1, 8);
            s2 += __shfl_xor(s2, 1, 8); s3 += __shfl_xor(s3, 1, 8);
            s0 += __shfl_xor(s0, 2, 8); s1 += __shfl_xor(s1, 2, 8);
            s2 += __shfl_xor(s2, 2, 8); s3 += __shfl_xor(s3, 2, 8);
            s0 += __shfl_xor(s0, 4, 8); s1 += __shfl_xor(s1, 4, 8);
            s2 += __shfl_xor(s2, 4, 8); s3 += __shfl_xor(s3, 4, 8);
            zacc += s0 + s1 + s2 + s3;
            macc += s0 * vn0 + s1 * vn1 + s2 * vn2 + s3 * vn3;
        }
        float Z = 1.f / (zacc + 1e-6f);
        float msg = macc * Z;
        float mo = 0.f;
#pragma unroll
        for (int c = 0; c < 32; ++c) mo += __shfl(msg, c, 32) * wmL[c][lane];
        float mean = mo;
#pragma unroll
        for (int m = 16; m >= 1; m >>= 1) mean += __shfl_xor(mean, m, 32);
        mean *= (1.f / 32.f);
        float d = mo - mean;
        float var = d * d;
#pragma unroll
        for (int m = 16; m >= 1; m >>= 1) var += __shfl_xor(var, m, 32);
        var *= (1.f / 32.f);
        float msgn = l1g * d * rsqrtf(var + 1e-5f) + l1b;
        float h0 = 0.f, h1 = 0.f;
#pragma unroll
        for (int c = 0; c < 32; ++c) {
            float xc = __shfl(x, c, 32);
            float mc = __shfl(msgn, c, 32);
            h0 += xc * w1L[c][lane]      + mc * w1L[c + 32][lane];
            h1 += xc * w1L[c][lane + 32] + mc * w1L[c + 32][lane + 32];
        }
        h0 = fmaxf(h0, 0.f); h1 = fmaxf(h1, 0.f);
        float o = 0.f;
#pragma unroll
        for (int c = 0; c < 32; ++c) {
            o += __shfl(h0, c, 32) * w2L[c][lane] + __shfl(h1, c, 32) * w2L[c + 32][lane];
        }
        float mean2 = o;
#pragma unroll
        for (int m = 16; m >= 1; m >>= 1) mean2 += __shfl_xor(mean2, m, 32);
        mean2 *= (1.f / 32.f);
        float d2 = o - mean2;
        float var2 = d2 * d2;
#pragma unroll
        for (int m = 16; m >= 1; m >>= 1) var2 += __shfl_xor(var2, m, 32);
        var2 *= (1.f / 32.f);
        float on = l2g * d2 * rsqrtf(var2 + 1e-5f) + l2b;
        otile[lane][i * 8 + g] = x + on;
    }
    __syncthreads();
    int nn = t & 31, cr = t >> 5;
    int nb = p0 % NN;
#pragma unroll
    for (int r = 0; r < 4; ++r) {
        int c = r * 8 + cr;
        out[((size_t)b * 32 + c) * NN + nb + nn] = otile[c][nn];
    }
}

extern "C" void kernel_launch(void* const* d_in, const int* in_sizes, int n_in,
                              void* d_out, int out_size, void* d_ws, size_t ws_size,
                              hipStream_t stream) {
    const float* feat   = (const float*)d_in[0];
    const float* xyz    = (const float*)d_in[1];
    const float* w_pos1 = (const float*)d_in[2];
    const float* b_pos1 = (const float*)d_in[3];
    const float* w_pos2 = (const float*)d_in[4];
    const float* b_pos2 = (const float*)d_in[5];
    const float* w_q    = (const float*)d_in[6];
    const float* w_k    = (const float*)d_in[7];
    const float* w_v    = (const float*)d_in[8];
    const float* w_mg   = (const float*)d_in[9];
    const float* ln1_g  = (const float*)d_in[10];
    const float* ln1_b  = (const float*)d_in[11];
    const float* w_mlp1 = (const float*)d_in[12];
    const float* w_mlp2 = (const float*)d_in[13];
    const float* ln2_g  = (const float*)d_in[14];
    const float* ln2_b  = (const float*)d_in[15];
    float* ws = (float*)d_ws;
    float* xt = ws + OFF_XT;
    float* Qf = ws + OFF_QF;
    float* Kf = ws + OFF_KF;
    float* Vn = ws + OFF_VN;
    float* xx = ws + OFF_XX;
    unsigned* idxg = (unsigned*)(ws + OFF_IDX);
    _Float16* Xh = (_Float16*)(ws + OFF_XH);
    _Float16* Xl = (_Float16*)(ws + OFF_XL);
    float* out = (float*)d_out;

    k_transpose<<<dim3(64, 8), 256, 0, stream>>>(feat, xt, Xh, Xl, xx);
    k_prep<<<1024, 256, 0, stream>>>(xt, xyz, w_pos1, b_pos1, w_pos2, b_pos2,
                                     w_q, w_k, w_v, Qf, Kf, Vn);
    k_knn<<<1024, 256, 0, stream>>>(Xh, Xl, xt, xx, idxg);
    k_attn<<<1024, 256, 0, stream>>>(xt, Qf, Kf, Vn, idxg, w_mg, ln1_g, ln1_b,
                                     w_mlp1, w_mlp2, ln2_g, ln2_b, out);
}

// Round 6
// 247.335 us; speedup vs baseline: 8.8437x; 1.5813x over previous
//
#include <hip/hip_runtime.h>
#include <math.h>

#define BB 8
#define CC 32
#define NN 4096
#define KNN 32
#define NP (BB*NN)   // 32768

// workspace float offsets
#define OFF_XT  0u
#define OFF_QF  1048576u
#define OFF_KV  2097152u   // 2M floats: 32 x float2 per point
#define OFF_XX  4194304u
#define OFF_IDX 4227072u   // 1M u32
#define OFF_XH  5275648u   // 1M f16
#define OFF_XL  5799936u   // 1M f16
#define OFF_MSG 5275648u   // overlaps XH/XL (dead after k_knn)

typedef _Float16 f16x8 __attribute__((ext_vector_type(8)));
typedef float f32x4 __attribute__((ext_vector_type(4)));
#define MFMA16(A,B,C) __builtin_amdgcn_mfma_f32_16x16x32_f16(A,B,C,0,0,0)

__device__ __forceinline__ float elu1(float x) {
    return x > 0.f ? x + 1.f : expf(x);
}

// ---------------- K1: transpose feat[B,C,N] -> xt[B,N,C] + Xh/Xl/xx ----------------
__global__ __launch_bounds__(256) void k_transpose(const float* __restrict__ feat,
                                                   float* __restrict__ xt,
                                                   _Float16* __restrict__ Xh,
                                                   _Float16* __restrict__ Xl,
                                                   float* __restrict__ xx) {
    __shared__ float tile[32][65];
    int b = blockIdx.y;
    int n0 = blockIdx.x * 64;
    int t = threadIdx.x;
    int nn = t & 63, cr = t >> 6;
#pragma unroll
    for (int r = 0; r < 8; ++r) {
        int c = r * 4 + cr;
        tile[c][nn] = feat[((size_t)b * 32 + c) * NN + n0 + nn];
    }
    __syncthreads();
    int c2 = t & 31, nr = t >> 5;
#pragma unroll
    for (int r = 0; r < 8; ++r) {
        int nl = r * 8 + nr;
        size_t gi = ((size_t)b * NN + n0 + nl) * 32 + c2;
        float v = tile[c2][nl];
        xt[gi] = v;
        _Float16 hv = (_Float16)v;
        Xh[gi] = hv;
        Xl[gi] = (_Float16)(v - (float)hv);
    }
    if (t < 64) {
        float s = 0.f;
#pragma unroll
        for (int c = 0; c < 32; ++c) { float u = tile[c][t]; s += u * u; }
        xx[(size_t)b * NN + n0 + t] = s;
    }
}

// ---------------- K2: per-point prep (weights in LDS) ----------------
__global__ __launch_bounds__(256, 2) void k_prep(
        const float* __restrict__ xt, const float* __restrict__ xyz,
        const float* __restrict__ w_pos1, const float* __restrict__ b_pos1,
        const float* __restrict__ w_pos2, const float* __restrict__ b_pos2,
        const float* __restrict__ w_q, const float* __restrict__ w_k,
        const float* __restrict__ w_v,
        float* __restrict__ Qf, float* __restrict__ KV) {
    __shared__ float sW2[1024], sWq[1024], sWk[1024], sWv[1024];
    int t = threadIdx.x;
    for (int i = t; i < 1024; i += 256) {
        sW2[i] = w_pos2[i];
        sWq[i] = w_q[i];
        sWk[i] = w_k[i];
        sWv[i] = w_v[i];
    }
    int lane = t & 31;
    int g = t >> 5;
    float w1c0 = w_pos1[lane], w1c1 = w_pos1[32 + lane], w1c2 = w_pos1[64 + lane];
    float b1c = b_pos1[lane], b2c = b_pos2[lane];
    __syncthreads();
#pragma unroll 1
    for (int p = blockIdx.x * 8 + g; p < NP; p += gridDim.x * 8) {
        asm volatile("" ::: "memory");
        float x0 = xyz[(size_t)p * 3 + 0];
        float x1 = xyz[(size_t)p * 3 + 1];
        float x2 = xyz[(size_t)p * 3 + 2];
        float h = fmaxf(x0 * w1c0 + x1 * w1c1 + x2 * w1c2 + b1c, 0.f);
        float P = b2c;
#pragma unroll 8
        for (int j = 0; j < 32; ++j) P += __shfl(h, j, 32) * sW2[j * 32 + lane];
        float xv = xt[(size_t)p * 32 + lane];
        float qin = xv + P;
        float qa = 0.f, ka = 0.f, va = 0.f;
#pragma unroll 8
        for (int j = 0; j < 32; ++j) {
            float qj = __shfl(qin, j, 32);
            qa += qj * sWq[j * 32 + lane];
            ka += qj * sWk[j * 32 + lane];
            va += qj * sWv[j * 32 + lane];
        }
        Qf[(size_t)p * 32 + lane] = elu1(qa);
        float2 kvv;
        kvv.x = elu1(ka);
        kvv.y = va;   // raw V ((V/k)*k cancels exactly)
        *(((float2*)(KV + (size_t)p * 64)) + lane) = kvv;
    }
}

// ---------------- K3: KNN via MFMA + 128-bucket hist, float-threshold sweep2 ----------------
__global__ __launch_bounds__(256, 4) void k_knn(
        const _Float16* __restrict__ Xh, const _Float16* __restrict__ Xl,
        const float* __restrict__ xt, const float* __restrict__ xx,
        unsigned* __restrict__ idxg) {
    __shared__ unsigned histU[32 * 128];   // 16 KB, u32 buckets
    __shared__ unsigned outIdx[32][32];    // 4 KB
    __shared__ unsigned tieIdx[32][96];    // 12 KB
    __shared__ int sT[32];
    __shared__ unsigned sBase[32];
    __shared__ unsigned outCnt[32], tieCnt[32];
    __shared__ float sM2;
    __shared__ float redbuf[4];

    int bid = blockIdx.x;
    int b = bid & 7;                 // XCD swizzle: batch per XCD
    int n0 = (bid >> 3) << 5;        // 32 rows per block
    int t = threadIdx.x;
    int lane = t & 63, wv = t >> 6;
    size_t bbase = (size_t)b * NN;

    for (int i = t; i < 4096; i += 256) histU[i] = 0u;
    if (t < 32) { outCnt[t] = 0u; tieCnt[t] = 0u; }

    float lm = 0.f;
    for (int i = t; i < NN; i += 256) lm = fmaxf(lm, xx[bbase + i]);
#pragma unroll
    for (int off = 32; off >= 1; off >>= 1) lm = fmaxf(lm, __shfl_xor(lm, off, 64));
    if (lane == 0) redbuf[wv] = lm;
    __syncthreads();
    if (t == 0) sM2 = fmaxf(fmaxf(redbuf[0], redbuf[1]), fmaxf(redbuf[2], redbuf[3]));
    __syncthreads();
    float M2 = sM2;

    int al = lane & 15;
    int kgrp = lane >> 4;
    int ak = kgrp * 8;
    const _Float16* Xhb = Xh + bbase * 32;
    const _Float16* Xlb = Xl + bbase * 32;
    const float* xxb = xx + bbase;
    f16x8 Ah0 = *(const f16x8*)(Xhb + (size_t)(n0 + al) * 32 + ak);
    f16x8 Al0 = *(const f16x8*)(Xlb + (size_t)(n0 + al) * 32 + ak);
    f16x8 Ah1 = *(const f16x8*)(Xhb + (size_t)(n0 + 16 + al) * 32 + ak);
    f16x8 Al1 = *(const f16x8*)(Xlb + (size_t)(n0 + 16 + al) * 32 + ak);

    const float C511 = 511.96f;
    float sc2[8], scn[8], c0a[8];
    unsigned rowW[8];
#pragma unroll
    for (int r = 0; r < 8; ++r) {
        int rowloc = (r < 4 ? 0 : 16) + kgrp * 4 + (r & 3);
        float xxi = xxb[n0 + rowloc];
        float scale = C511 / (2.f * (xxi + M2));
        sc2[r] = scale + scale;
        scn[r] = -scale;
        c0a[r] = __builtin_fmaf(-xxi, scale, C511);
        rowW[r] = (unsigned)rowloc * 128u;
    }

    unsigned cp0 = (unsigned)(wv * 1024 + al);
    unsigned akB = (unsigned)ak * 2u;
    const char* XhbB = (const char*)Xhb;
    const char* XlbB = (const char*)Xlb;

    // ---- sweep 1: histogram (pipelined) ----
    {
        f16x8 Bh_c = *(const f16x8*)(XhbB + cp0 * 64u + akB);
        f16x8 Bl_c = *(const f16x8*)(XlbB + cp0 * 64u + akB);
        float xxj_c = xxb[cp0];
#pragma unroll 1
        for (int tt = 0; tt < 64; ++tt) {
            unsigned cpn = cp0 + (unsigned)(((tt + 1) & 63) << 4);
            f16x8 Bh_n = *(const f16x8*)(XhbB + cpn * 64u + akB);
            f16x8 Bl_n = *(const f16x8*)(XlbB + cpn * 64u + akB);
            float xxj_n = xxb[cpn];
            f32x4 z = {0.f, 0.f, 0.f, 0.f};
            f32x4 u0 = MFMA16(Al0, Bl_c, z); u0 = MFMA16(Ah0, Bl_c, u0);
            f32x4 w0 = MFMA16(Al0, Bh_c, z); w0 = MFMA16(Ah0, Bh_c, w0);
            f32x4 u1 = MFMA16(Al1, Bl_c, z); u1 = MFMA16(Ah1, Bl_c, u1);
            f32x4 w1 = MFMA16(Al1, Bh_c, z); w1 = MFMA16(Ah1, Bh_c, w1);
            float bcol[8];
#pragma unroll
            for (int r = 0; r < 8; ++r) bcol[r] = __builtin_fmaf(xxj_c, scn[r], c0a[r]);
#pragma unroll
            for (int r = 0; r < 8; ++r) {
                float a = (r < 4) ? (u0[r] + w0[r]) : (u1[r - 4] + w1[r - 4]);
                float qf = __builtin_fmaf(a, sc2[r], bcol[r]);
                unsigned q = (unsigned)fmaxf(qf, 0.f);
                q = q > 511u ? 511u : q;
                atomicAdd(&histU[rowW[r] + (q >> 2)], 1u);
            }
            Bh_c = Bh_n; Bl_c = Bl_n; xxj_c = xxj_n;
        }
    }
    __syncthreads();

    // ---- scan: per row suffix over 128 buckets -> T, base ----
#pragma unroll 1
    for (int rr = 0; rr < 8; ++rr) {
        int row = wv * 8 + rr;
        const unsigned* Hr = histU + row * 128;
        unsigned cl = Hr[2 * lane], ch = Hr[2 * lane + 1];
        unsigned ss = cl + ch;
        unsigned acc = ss;
#pragma unroll
        for (int off = 1; off < 64; off <<= 1) {
            unsigned vv = __shfl_down(acc, off, 64);
            if (lane + off < 64) acc += vv;
        }
        unsigned run = acc - ss;
        int Tl = -1; unsigned bl = 0;
        if (run < 32u && run + ch >= 32u) { Tl = 2 * lane + 1; bl = run; }
        run += ch;
        if (Tl < 0 && run < 32u && run + cl >= 32u) { Tl = 2 * lane; bl = run; }
        unsigned long long bal = __ballot(Tl >= 0);
        int src = __ffsll(bal) - 1;
        int Tv = __shfl(Tl, src, 64);
        unsigned bv = (unsigned)__shfl((int)bl, src, 64);
        if (lane == 0) { sT[row] = Tv; sBase[row] = bv; }
    }
    __syncthreads();

    float Tin[8], Tlo[8];
#pragma unroll
    for (int r = 0; r < 8; ++r) {
        int T = sT[rowW[r] >> 7];
        Tin[r] = (float)(4 * T + 4);
        Tlo[r] = (T == 0) ? -3.0e38f : (float)(4 * T);
    }

    // ---- sweep 2: identical qf recompute, float-threshold emit ----
    {
        f16x8 Bh_c = *(const f16x8*)(XhbB + cp0 * 64u + akB);
        f16x8 Bl_c = *(const f16x8*)(XlbB + cp0 * 64u + akB);
        float xxj_c = xxb[cp0];
#pragma unroll 1
        for (int tt = 0; tt < 64; ++tt) {
            unsigned cp = cp0 + (unsigned)(tt << 4);
            unsigned cpn = cp0 + (unsigned)(((tt + 1) & 63) << 4);
            f16x8 Bh_n = *(const f16x8*)(XhbB + cpn * 64u + akB);
            f16x8 Bl_n = *(const f16x8*)(XlbB + cpn * 64u + akB);
            float xxj_n = xxb[cpn];
            f32x4 z = {0.f, 0.f, 0.f, 0.f};
            f32x4 u0 = MFMA16(Al0, Bl_c, z); u0 = MFMA16(Ah0, Bl_c, u0);
            f32x4 w0 = MFMA16(Al0, Bh_c, z); w0 = MFMA16(Ah0, Bh_c, w0);
            f32x4 u1 = MFMA16(Al1, Bl_c, z); u1 = MFMA16(Ah1, Bl_c, u1);
            f32x4 w1 = MFMA16(Al1, Bh_c, z); w1 = MFMA16(Ah1, Bh_c, w1);
            float bcol[8];
#pragma unroll
            for (int r = 0; r < 8; ++r) bcol[r] = __builtin_fmaf(xxj_c, scn[r], c0a[r]);
#pragma unroll
            for (int r = 0; r < 8; ++r) {
                float a = (r < 4) ? (u0[r] + w0[r]) : (u1[r - 4] + w1[r - 4]);
                float qf = __builtin_fmaf(a, sc2[r], bcol[r]);
                if (qf >= Tlo[r]) {
                    unsigned row = rowW[r] >> 7;
                    if (qf >= Tin[r]) {
                        unsigned pos = atomicAdd(&outCnt[row], 1u);
                        outIdx[row][pos] = cp;
                    } else {
                        unsigned tp = atomicAdd(&tieCnt[row], 1u);
                        if (tp < 96u) tieIdx[row][tp] = cp;
                    }
                }
            }
            Bh_c = Bh_n; Bl_c = Bl_n; xxj_c = xxj_n;
        }
    }
    __syncthreads();

    // ---- resolve boundary bucket with exact fp32 scores ----
#pragma unroll 1
    for (int rr = 0; rr < 8; ++rr) {
        int row = wv * 8 + rr;
        int gr = n0 + row;
        unsigned bA = sBase[row];
        int need = 32 - (int)bA;
        if (need <= 0) continue;
        int nt = (int)tieCnt[row]; if (nt > 96) nt = 96;
        const float* xr = xt + (bbase + gr) * 32;
        float xxi_r = xxb[gr];
        float v0 = -INFINITY, v1 = -INFINITY;
        int i0 = 0x7fffffff, i1 = 0x7fffffff;
        bool a0v = lane < nt, a1v = lane + 64 < nt;
        if (a0v) {
            int c = (int)tieIdx[row][lane];
            const float* xc = xt + (bbase + c) * 32;
            float dot = 0.f;
#pragma unroll
            for (int ch = 0; ch < 32; ch += 4) {
                float4 rv = *(const float4*)(xr + ch);
                float4 cv = *(const float4*)(xc + ch);
                dot = __builtin_fmaf(rv.x, cv.x, dot);
                dot = __builtin_fmaf(rv.y, cv.y, dot);
                dot = __builtin_fmaf(rv.z, cv.z, dot);
                dot = __builtin_fmaf(rv.w, cv.w, dot);
            }
            v0 = 2.f * dot - xxi_r - xxb[c];
            i0 = c;
        }
        if (a1v) {
            int c = (int)tieIdx[row][lane + 64];
            const float* xc = xt + (bbase + c) * 32;
            float dot = 0.f;
#pragma unroll
            for (int ch = 0; ch < 32; ch += 4) {
                float4 rv = *(const float4*)(xr + ch);
                float4 cv = *(const float4*)(xc + ch);
                dot = __builtin_fmaf(rv.x, cv.x, dot);
                dot = __builtin_fmaf(rv.y, cv.y, dot);
                dot = __builtin_fmaf(rv.z, cv.z, dot);
                dot = __builtin_fmaf(rv.w, cv.w, dot);
            }
            v1 = 2.f * dot - xxi_r - xxb[c];
            i1 = c;
        }
        for (int it = 0; it < need; ++it) {
            float bvv = -INFINITY; int bj2 = 0x7fffffff;
            if (a0v && (v0 > bvv || (v0 == bvv && i0 < bj2))) { bvv = v0; bj2 = i0; }
            if (a1v && (v1 > bvv || (v1 == bvv && i1 < bj2))) { bvv = v1; bj2 = i1; }
#pragma unroll
            for (int off = 1; off < 64; off <<= 1) {
                float ov = __shfl_xor(bvv, off, 64);
                int oj = __shfl_xor(bj2, off, 64);
                if (ov > bvv || (ov == bvv && oj < bj2)) { bvv = ov; bj2 = oj; }
            }
            if (a0v && i0 == bj2) a0v = false;
            if (a1v && i1 == bj2) a1v = false;
            if (lane == 0) outIdx[row][bA + it] = (unsigned)bj2;
        }
    }
    __syncthreads();

    for (int i = t; i < 1024; i += 256)
        idxg[(bbase + n0 + (i >> 5)) * 32 + (i & 31)] = outIdx[i >> 5][i & 31];
}

// ---------------- K4: attention gather only -> msg ----------------
__global__ __launch_bounds__(256) void k_attn(
        const float* __restrict__ Qf, const float* __restrict__ KV,
        const unsigned* __restrict__ idxg, float* __restrict__ msg) {
    int t = threadIdx.x;
    int wv = t >> 6, lane = t & 63;
    int l32 = lane & 31;
    int p = blockIdx.x * 8 + wv * 2 + (lane >> 5);
    int b = p >> 12;
    size_t bbase = (size_t)b * NN;
    const char* KVb = (const char*)(KV + bbase * 64);
    float q = Qf[(size_t)p * 32 + l32];
    int jv = (int)idxg[(size_t)p * 32 + l32];
    unsigned laneoff = (unsigned)l32 * 8u;
    float zacc = 0.f, macc = 0.f;
#pragma unroll 8
    for (int k = 0; k < 32; ++k) {
        int j = __shfl(jv, k, 32);
        unsigned off = ((unsigned)j << 8) + laneoff;
        float2 kv = *(const float2*)(KVb + off);
        float s = q * kv.x;
        s += __shfl_xor(s, 1, 8);
        s += __shfl_xor(s, 2, 8);
        s += __shfl_xor(s, 4, 8);
        zacc += s;
        macc = __builtin_fmaf(s, kv.y, macc);
    }
    float Z = 1.f / (zacc + 1e-6f);
    msg[(size_t)p * 32 + l32] = macc * Z;
}

// ---------------- K5: merge + LN1 + MLP + LN2 + residual + transpose (MFMA) ----------------
__global__ __launch_bounds__(256, 2) void k_post(
        const float* __restrict__ msg, const float* __restrict__ xt,
        const float* __restrict__ w_merge,
        const float* __restrict__ ln1_g, const float* __restrict__ ln1_b,
        const float* __restrict__ w_mlp1, const float* __restrict__ w_mlp2,
        const float* __restrict__ ln2_g, const float* __restrict__ ln2_b,
        float* __restrict__ out) {
    __shared__ _Float16 wmT[2][32][32];
    __shared__ _Float16 w1T[2][64][64];
    __shared__ _Float16 w2T[2][32][64];
    __shared__ _Float16 sPh[4][16][40], sPl[4][16][40];
    __shared__ _Float16 sHh[4][16][72], sHl[4][16][72];
    int t = threadIdx.x;
    for (int i = t; i < 1024; i += 256) {
        float v = w_merge[i]; int in = i >> 5, o = i & 31;
        _Float16 h = (_Float16)v;
        wmT[0][o][in] = h; wmT[1][o][in] = (_Float16)(v - (float)h);
    }
    for (int i = t; i < 4096; i += 256) {
        float v = w_mlp1[i]; int in = i >> 6, o = i & 63;
        _Float16 h = (_Float16)v;
        w1T[0][o][in] = h; w1T[1][o][in] = (_Float16)(v - (float)h);
    }
    for (int i = t; i < 2048; i += 256) {
        float v = w_mlp2[i]; int in = i >> 5, o = i & 31;
        _Float16 h = (_Float16)v;
        w2T[0][o][in] = h; w2T[1][o][in] = (_Float16)(v - (float)h);
    }
    int wv = t >> 6, lane = t & 63;
    int row = lane & 15, kg = lane >> 4;
    int p0 = blockIdx.x * 64 + wv * 16;
    int b = p0 >> 12;
    float g1a = ln1_g[row], b1a = ln1_b[row], g1b = ln1_g[row + 16], b1b = ln1_b[row + 16];
    float g2a = ln2_g[row], b2a = ln2_b[row], g2b = ln2_g[row + 16], b2b = ln2_b[row + 16];
    __syncthreads();

    f32x4 z4 = {0.f, 0.f, 0.f, 0.f};
    // A_msg hi/lo
    f16x8 Amh, Aml;
    {
        const float* mr = msg + (size_t)(p0 + row) * 32 + kg * 8;
#pragma unroll
        for (int j = 0; j < 8; ++j) {
            float v = mr[j];
            _Float16 h = (_Float16)v;
            Amh[j] = h; Aml[j] = (_Float16)(v - (float)h);
        }
    }
    f32x4 accM[2];
#pragma unroll
    for (int n = 0; n < 2; ++n) {
        f16x8 Bh = *(const f16x8*)&wmT[0][n * 16 + row][kg * 8];
        f16x8 Bl = *(const f16x8*)&wmT[1][n * 16 + row][kg * 8];
        f32x4 a = z4;
        a = MFMA16(Aml, Bl, a); a = MFMA16(Amh, Bl, a);
        a = MFMA16(Aml, Bh, a); a = MFMA16(Amh, Bh, a);
        accM[n] = a;
    }
    // LN1 -> msgn packed hi/lo in LDS
#pragma unroll
    for (int r = 0; r < 4; ++r) {
        float s0 = accM[0][r], s1 = accM[1][r];
        float sm = s0 + s1;
        sm += __shfl_xor(sm, 1, 64); sm += __shfl_xor(sm, 2, 64);
        sm += __shfl_xor(sm, 4, 64); sm += __shfl_xor(sm, 8, 64);
        float mean = sm * (1.f / 32.f);
        float d0 = s0 - mean, d1 = s1 - mean;
        float vv = d0 * d0 + d1 * d1;
        vv += __shfl_xor(vv, 1, 64); vv += __shfl_xor(vv, 2, 64);
        vv += __shfl_xor(vv, 4, 64); vv += __shfl_xor(vv, 8, 64);
        float rst = rsqrtf(vv * (1.f / 32.f) + 1e-5f);
        float m0 = g1a * d0 * rst + b1a;
        float m1 = g1b * d1 * rst + b1b;
        int pl = kg * 4 + r;
        _Float16 h0 = (_Float16)m0;
        sPh[wv][pl][row] = h0; sPl[wv][pl][row] = (_Float16)(m0 - (float)h0);
        _Float16 h1 = (_Float16)m1;
        sPh[wv][pl][row + 16] = h1; sPl[wv][pl][row + 16] = (_Float16)(m1 - (float)h1);
    }
    __syncthreads();
    // A_xt hi/lo
    f16x8 Axh, Axl;
    {
        const float* xr = xt + (size_t)(p0 + row) * 32 + kg * 8;
#pragma unroll
        for (int j = 0; j < 8; ++j) {
            float v = xr[j];
            _Float16 h = (_Float16)v;
            Axh[j] = h; Axl[j] = (_Float16)(v - (float)h);
        }
    }
    f16x8 Aph = *(const f16x8*)&sPh[wv][row][kg * 8];
    f16x8 Apl = *(const f16x8*)&sPl[wv][row][kg * 8];
    // mlp1 (K=64: xt | msgn), relu
    f32x4 accH[4];
#pragma unroll
    for (int n = 0; n < 4; ++n) {
        f16x8 B0h = *(const f16x8*)&w1T[0][n * 16 + row][kg * 8];
        f16x8 B0l = *(const f16x8*)&w1T[1][n * 16 + row][kg * 8];
        f16x8 B1h = *(const f16x8*)&w1T[0][n * 16 + row][32 + kg * 8];
        f16x8 B1l = *(const f16x8*)&w1T[1][n * 16 + row][32 + kg * 8];
        f32x4 a = z4;
        a = MFMA16(Axl, B0l, a); a = MFMA16(Axh, B0l, a);
        a = MFMA16(Axl, B0h, a); a = MFMA16(Axh, B0h, a);
        a = MFMA16(Apl, B1l, a); a = MFMA16(Aph, B1l, a);
        a = MFMA16(Apl, B1h, a); a = MFMA16(Aph, B1h, a);
        accH[n] = a;
    }
#pragma unroll
    for (int n = 0; n < 4; ++n) {
#pragma unroll
        for (int r = 0; r < 4; ++r) {
            float hv = fmaxf(accH[n][r], 0.f);
            int pl = kg * 4 + r;
            _Float16 hh = (_Float16)hv;
            sHh[wv][pl][n * 16 + row] = hh;
            sHl[wv][pl][n * 16 + row] = (_Float16)(hv - (float)hh);
        }
    }
    __syncthreads();
    f16x8 Hh0 = *(const f16x8*)&sHh[wv][row][kg * 8];
    f16x8 Hl0 = *(const f16x8*)&sHl[wv][row][kg * 8];
    f16x8 Hh1 = *(const f16x8*)&sHh[wv][row][32 + kg * 8];
    f16x8 Hl1 = *(const f16x8*)&sHl[wv][row][32 + kg * 8];
    f32x4 accO[2];
#pragma unroll
    for (int n = 0; n < 2; ++n) {
        f16x8 B0h = *(const f16x8*)&w2T[0][n * 16 + row][kg * 8];
        f16x8 B0l = *(const f16x8*)&w2T[1][n * 16 + row][kg * 8];
        f16x8 B1h = *(const f16x8*)&w2T[0][n * 16 + row][32 + kg * 8];
        f16x8 B1l = *(const f16x8*)&w2T[1][n * 16 + row][32 + kg * 8];
        f32x4 a = z4;
        a = MFMA16(Hl0, B0l, a); a = MFMA16(Hh0, B0l, a);
        a = MFMA16(Hl0, B0h, a); a = MFMA16(Hh0, B0h, a);
        a = MFMA16(Hl1, B1l, a); a = MFMA16(Hh1, B1l, a);
        a = MFMA16(Hl1, B1h, a); a = MFMA16(Hh1, B1h, a);
        accO[n] = a;
    }
    // LN2 + residual + transposed store
#pragma unroll
    for (int r = 0; r < 4; ++r) {
        float s0 = accO[0][r], s1 = accO[1][r];
        float sm = s0 + s1;
        sm += __shfl_xor(sm, 1, 64); sm += __shfl_xor(sm, 2, 64);
        sm += __shfl_xor(sm, 4, 64); sm += __shfl_xor(sm, 8, 64);
        float mean = sm * (1.f / 32.f);
        float d0 = s0 - mean, d1 = s1 - mean;
        float vv = d0 * d0 + d1 * d1;
        vv += __shfl_xor(vv, 1, 64); vv += __shfl_xor(vv, 2, 64);
        vv += __shfl_xor(vv, 4, 64); vv += __shfl_xor(vv, 8, 64);
        float rst = rsqrtf(vv * (1.f / 32.f) + 1e-5f);
        float o0 = g2a * d0 * rst + b2a;
        float o1 = g2b * d1 * rst + b2b;
        int pt = p0 + kg * 4 + r;
        int nb = pt & 4095;
        float xv0 = xt[(size_t)pt * 32 + row];
        float xv1 = xt[(size_t)pt * 32 + row + 16];
        out[((size_t)b * 32 + row) * 4096 + nb] = xv0 + o0;
        out[((size_t)b * 32 + row + 16) * 4096 + nb] = xv1 + o1;
    }
}

extern "C" void kernel_launch(void* const* d_in, const int* in_sizes, int n_in,
                              void* d_out, int out_size, void* d_ws, size_t ws_size,
                              hipStream_t stream) {
    const float* feat   = (const float*)d_in[0];
    const float* xyz    = (const float*)d_in[1];
    const float* w_pos1 = (const float*)d_in[2];
    const float* b_pos1 = (const float*)d_in[3];
    const float* w_pos2 = (const float*)d_in[4];
    const float* b_pos2 = (const float*)d_in[5];
    const float* w_q    = (const float*)d_in[6];
    const float* w_k    = (const float*)d_in[7];
    const float* w_v    = (const float*)d_in[8];
    const float* w_mg   = (const float*)d_in[9];
    const float* ln1_g  = (const float*)d_in[10];
    const float* ln1_b  = (const float*)d_in[11];
    const float* w_mlp1 = (const float*)d_in[12];
    const float* w_mlp2 = (const float*)d_in[13];
    const float* ln2_g  = (const float*)d_in[14];
    const float* ln2_b  = (const float*)d_in[15];
    float* ws = (float*)d_ws;
    float* xt = ws + OFF_XT;
    float* Qf = ws + OFF_QF;
    float* KVp = ws + OFF_KV;
    float* xx = ws + OFF_XX;
    unsigned* idxg = (unsigned*)(ws + OFF_IDX);
    _Float16* Xh = (_Float16*)(ws + OFF_XH);
    _Float16* Xl = (_Float16*)(ws + OFF_XL);
    float* msg = ws + OFF_MSG;
    float* out = (float*)d_out;

    k_transpose<<<dim3(64, 8), 256, 0, stream>>>(feat, xt, Xh, Xl, xx);
    k_prep<<<1024, 256, 0, stream>>>(xt, xyz, w_pos1, b_pos1, w_pos2, b_pos2,
                                     w_q, w_k, w_v, Qf, KVp);
    k_knn<<<1024, 256, 0, stream>>>(Xh, Xl, xt, xx, idxg);
    k_attn<<<4096, 256, 0, stream>>>(Qf, KVp, idxg, msg);
    k_post<<<512, 256, 0, stream>>>(msg, xt, w_mg, ln1_g, ln1_b,
                                    w_mlp1, w_mlp2, ln2_g, ln2_b, out);
}

// Round 7
// 242.801 us; speedup vs baseline: 9.0088x; 1.0187x over previous
//
#include <hip/hip_runtime.h>
#include <math.h>

#define BB 8
#define CC 32
#define NN 4096
#define KNN 32
#define NP (BB*NN)   // 32768

// workspace float offsets
#define OFF_XT  0u
#define OFF_QF  1048576u
#define OFF_KV  2097152u   // 2M floats: 32 x float2 per point
#define OFF_XX  4194304u
#define OFF_IDX 4227072u   // 1M u32
#define OFF_XH  5275648u   // 1M f16
#define OFF_XL  5799936u   // 1M f16
#define OFF_MSG 5275648u   // overlaps XH/XL (dead after k_knn)

typedef _Float16 f16x8 __attribute__((ext_vector_type(8)));
typedef float f32x4 __attribute__((ext_vector_type(4)));
#define MFMA16(A,B,C) __builtin_amdgcn_mfma_f32_16x16x32_f16(A,B,C,0,0,0)

__device__ __forceinline__ float elu1(float x) {
    return x > 0.f ? x + 1.f : expf(x);
}

// ---------------- K1: transpose feat[B,C,N] -> xt[B,N,C] + Xh/Xl/xx ----------------
__global__ __launch_bounds__(256) void k_transpose(const float* __restrict__ feat,
                                                   float* __restrict__ xt,
                                                   _Float16* __restrict__ Xh,
                                                   _Float16* __restrict__ Xl,
                                                   float* __restrict__ xx) {
    __shared__ float tile[32][65];
    int b = blockIdx.y;
    int n0 = blockIdx.x * 64;
    int t = threadIdx.x;
    int nn = t & 63, cr = t >> 6;
#pragma unroll
    for (int r = 0; r < 8; ++r) {
        int c = r * 4 + cr;
        tile[c][nn] = feat[((size_t)b * 32 + c) * NN + n0 + nn];
    }
    __syncthreads();
    int c2 = t & 31, nr = t >> 5;
#pragma unroll
    for (int r = 0; r < 8; ++r) {
        int nl = r * 8 + nr;
        size_t gi = ((size_t)b * NN + n0 + nl) * 32 + c2;
        float v = tile[c2][nl];
        xt[gi] = v;
        _Float16 hv = (_Float16)v;
        Xh[gi] = hv;
        Xl[gi] = (_Float16)(v - (float)hv);
    }
    if (t < 64) {
        float s = 0.f;
#pragma unroll
        for (int c = 0; c < 32; ++c) { float u = tile[c][t]; s += u * u; }
        xx[(size_t)b * NN + n0 + t] = s;
    }
}

// ---------------- K2: per-point prep (weights in LDS) ----------------
__global__ __launch_bounds__(256, 2) void k_prep(
        const float* __restrict__ xt, const float* __restrict__ xyz,
        const float* __restrict__ w_pos1, const float* __restrict__ b_pos1,
        const float* __restrict__ w_pos2, const float* __restrict__ b_pos2,
        const float* __restrict__ w_q, const float* __restrict__ w_k,
        const float* __restrict__ w_v,
        float* __restrict__ Qf, float* __restrict__ KV) {
    __shared__ float sW2[1024], sWq[1024], sWk[1024], sWv[1024];
    int t = threadIdx.x;
    for (int i = t; i < 1024; i += 256) {
        sW2[i] = w_pos2[i];
        sWq[i] = w_q[i];
        sWk[i] = w_k[i];
        sWv[i] = w_v[i];
    }
    int lane = t & 31;
    int g = t >> 5;
    float w1c0 = w_pos1[lane], w1c1 = w_pos1[32 + lane], w1c2 = w_pos1[64 + lane];
    float b1c = b_pos1[lane], b2c = b_pos2[lane];
    __syncthreads();
#pragma unroll 1
    for (int p = blockIdx.x * 8 + g; p < NP; p += gridDim.x * 8) {
        asm volatile("" ::: "memory");
        float x0 = xyz[(size_t)p * 3 + 0];
        float x1 = xyz[(size_t)p * 3 + 1];
        float x2 = xyz[(size_t)p * 3 + 2];
        float h = fmaxf(x0 * w1c0 + x1 * w1c1 + x2 * w1c2 + b1c, 0.f);
        float P = b2c;
#pragma unroll 8
        for (int j = 0; j < 32; ++j) P += __shfl(h, j, 32) * sW2[j * 32 + lane];
        float xv = xt[(size_t)p * 32 + lane];
        float qin = xv + P;
        float qa = 0.f, ka = 0.f, va = 0.f;
#pragma unroll 8
        for (int j = 0; j < 32; ++j) {
            float qj = __shfl(qin, j, 32);
            qa += qj * sWq[j * 32 + lane];
            ka += qj * sWk[j * 32 + lane];
            va += qj * sWv[j * 32 + lane];
        }
        Qf[(size_t)p * 32 + lane] = elu1(qa);
        float2 kvv;
        kvv.x = elu1(ka);
        kvv.y = va;   // raw V ((V/k)*k cancels exactly)
        *(((float2*)(KV + (size_t)p * 64)) + lane) = kvv;
    }
}

// ---------------- K3: KNN via MFMA + floor-filtered 128-bucket histogram ----------------
// Exactness: b1 = 32nd-best bucket of a 512-col subset <= true threshold bucket T
// (adding elements only raises the 32nd-best). Histogramming the remaining cols
// only where bucket >= b1 keeps all suffix counts at buckets >= b1 exact, so the
// final T and the selected set are identical to the unfiltered version.
__global__ __launch_bounds__(256, 4) void k_knn(
        const _Float16* __restrict__ Xh, const _Float16* __restrict__ Xl,
        const float* __restrict__ xt, const float* __restrict__ xx,
        unsigned* __restrict__ idxg) {
    __shared__ unsigned histU[32 * 132];   // 128 buckets/row, stride 132 (bank spread)
    __shared__ unsigned outIdx[32][32];
    __shared__ unsigned tieIdx[32][96];
    __shared__ int sT[32];
    __shared__ unsigned sBase[32];
    __shared__ float sFloor[32];
    __shared__ unsigned outCnt[32], tieCnt[32];
    __shared__ float sM2;
    __shared__ float redbuf[4];

    int bid = blockIdx.x;
    int b = bid & 7;                 // XCD swizzle: batch per XCD
    int n0 = (bid >> 3) << 5;        // 32 rows per block
    int t = threadIdx.x;
    int lane = t & 63, wv = t >> 6;
    size_t bbase = (size_t)b * NN;

    for (int i = t; i < 32 * 132; i += 256) histU[i] = 0u;
    if (t < 32) { outCnt[t] = 0u; tieCnt[t] = 0u; }

    float lm = 0.f;
    for (int i = t; i < NN; i += 256) lm = fmaxf(lm, xx[bbase + i]);
#pragma unroll
    for (int off = 32; off >= 1; off >>= 1) lm = fmaxf(lm, __shfl_xor(lm, off, 64));
    if (lane == 0) redbuf[wv] = lm;
    __syncthreads();
    if (t == 0) sM2 = fmaxf(fmaxf(redbuf[0], redbuf[1]), fmaxf(redbuf[2], redbuf[3]));
    __syncthreads();
    float M2 = sM2;

    int al = lane & 15;
    int kgrp = lane >> 4;
    int ak = kgrp * 8;
    const _Float16* Xhb = Xh + bbase * 32;
    const _Float16* Xlb = Xl + bbase * 32;
    const float* xxb = xx + bbase;
    f16x8 Ah0 = *(const f16x8*)(Xhb + (size_t)(n0 + al) * 32 + ak);
    f16x8 Al0 = *(const f16x8*)(Xlb + (size_t)(n0 + al) * 32 + ak);
    f16x8 Ah1 = *(const f16x8*)(Xhb + (size_t)(n0 + 16 + al) * 32 + ak);
    f16x8 Al1 = *(const f16x8*)(Xlb + (size_t)(n0 + 16 + al) * 32 + ak);

    const float C127 = 127.99f;
    float sc2[8], scn[8], c0a[8];
    unsigned rowW[8];
    int rowloc8[8];
#pragma unroll
    for (int r = 0; r < 8; ++r) {
        int rowloc = (r < 4 ? 0 : 16) + kgrp * 4 + (r & 3);
        float xxi = xxb[n0 + rowloc];
        float scale = C127 / (2.f * (xxi + M2));
        sc2[r] = scale + scale;
        scn[r] = -scale;
        c0a[r] = __builtin_fmaf(-xxi, scale, C127);
        rowW[r] = (unsigned)rowloc * 132u;
        rowloc8[r] = rowloc;
    }

    unsigned cp0 = (unsigned)(wv * 1024 + al);
    unsigned akB = (unsigned)ak * 2u;
    const char* XhbB = (const char*)Xhb;
    const char* XlbB = (const char*)Xlb;

    // ---- phase A: full histogram of first 512 cols (8 iters/wave) ----
#pragma unroll 1
    for (int tt = 0; tt < 8; ++tt) {
        unsigned cp = cp0 + (unsigned)(tt << 4);
        f16x8 Bh = *(const f16x8*)(XhbB + cp * 64u + akB);
        f16x8 Bl = *(const f16x8*)(XlbB + cp * 64u + akB);
        float xxj = xxb[cp];
        f32x4 z = {0.f, 0.f, 0.f, 0.f};
        f32x4 u0 = MFMA16(Al0, Bl, z); u0 = MFMA16(Ah0, Bl, u0);
        f32x4 w0 = MFMA16(Al0, Bh, z); w0 = MFMA16(Ah0, Bh, w0);
        f32x4 u1 = MFMA16(Al1, Bl, z); u1 = MFMA16(Ah1, Bl, u1);
        f32x4 w1 = MFMA16(Al1, Bh, z); w1 = MFMA16(Ah1, Bh, w1);
#pragma unroll
        for (int r = 0; r < 8; ++r) {
            float a = (r < 4) ? (u0[r] + w0[r]) : (u1[r - 4] + w1[r - 4]);
            float bcol = __builtin_fmaf(xxj, scn[r], c0a[r]);
            float qf = __builtin_fmaf(a, sc2[r], bcol);
            float qc = __builtin_amdgcn_fmed3f(qf, 0.f, C127);
            atomicAdd(&histU[rowW[r] + (unsigned)qc], 1u);
        }
    }
    __syncthreads();

    // ---- floor scan: per-row 32nd-best bucket of the 512-col subset ----
#pragma unroll 1
    for (int rr = 0; rr < 8; ++rr) {
        int row = wv * 8 + rr;
        const unsigned* Hr = histU + row * 132;
        unsigned cl = Hr[2 * lane], ch = Hr[2 * lane + 1];
        unsigned ss = cl + ch;
        unsigned acc = ss;
#pragma unroll
        for (int off = 1; off < 64; off <<= 1) {
            unsigned vv = __shfl_down(acc, off, 64);
            if (lane + off < 64) acc += vv;
        }
        unsigned run = acc - ss;
        int Tl = -1;
        if (run < 32u && run + ch >= 32u) Tl = 2 * lane + 1;
        run += ch;
        if (Tl < 0 && run < 32u && run + cl >= 32u) Tl = 2 * lane;
        unsigned long long bal = __ballot(Tl >= 0);
        int src = __ffsll(bal) - 1;
        int Tv = __shfl(Tl, src, 64);
        if (lane == 0) sFloor[row] = (Tv <= 0) ? -3.0e38f : (float)Tv;
    }
    __syncthreads();

    float fb1[8];
#pragma unroll
    for (int r = 0; r < 8; ++r) fb1[r] = sFloor[rowloc8[r]];

    // ---- phase B: filtered histogram of remaining 3584 cols (pipelined) ----
    {
        unsigned cpc = cp0 + (8u << 4);
        f16x8 Bh_c = *(const f16x8*)(XhbB + cpc * 64u + akB);
        f16x8 Bl_c = *(const f16x8*)(XlbB + cpc * 64u + akB);
        float xxj_c = xxb[cpc];
#pragma unroll 1
        for (int tt = 8; tt < 64; ++tt) {
            int tn = (tt + 1 < 64) ? (tt + 1) : 8;
            unsigned cpn = cp0 + (unsigned)(tn << 4);
            f16x8 Bh_n = *(const f16x8*)(XhbB + cpn * 64u + akB);
            f16x8 Bl_n = *(const f16x8*)(XlbB + cpn * 64u + akB);
            float xxj_n = xxb[cpn];
            f32x4 z = {0.f, 0.f, 0.f, 0.f};
            f32x4 u0 = MFMA16(Al0, Bl_c, z); u0 = MFMA16(Ah0, Bl_c, u0);
            f32x4 w0 = MFMA16(Al0, Bh_c, z); w0 = MFMA16(Ah0, Bh_c, w0);
            f32x4 u1 = MFMA16(Al1, Bl_c, z); u1 = MFMA16(Ah1, Bl_c, u1);
            f32x4 w1 = MFMA16(Al1, Bh_c, z); w1 = MFMA16(Ah1, Bh_c, w1);
            float bcol[8];
#pragma unroll
            for (int r = 0; r < 8; ++r) bcol[r] = __builtin_fmaf(xxj_c, scn[r], c0a[r]);
#pragma unroll
            for (int r = 0; r < 8; ++r) {
                float a = (r < 4) ? (u0[r] + w0[r]) : (u1[r - 4] + w1[r - 4]);
                float qf = __builtin_fmaf(a, sc2[r], bcol[r]);
                if (qf >= fb1[r]) {
                    float qc = __builtin_amdgcn_fmed3f(qf, 0.f, C127);
                    atomicAdd(&histU[rowW[r] + (unsigned)qc], 1u);
                }
            }
            Bh_c = Bh_n; Bl_c = Bl_n; xxj_c = xxj_n;
        }
    }
    __syncthreads();

    // ---- final scan: per-row suffix over 128 buckets -> T, base ----
#pragma unroll 1
    for (int rr = 0; rr < 8; ++rr) {
        int row = wv * 8 + rr;
        const unsigned* Hr = histU + row * 132;
        unsigned cl = Hr[2 * lane], ch = Hr[2 * lane + 1];
        unsigned ss = cl + ch;
        unsigned acc = ss;
#pragma unroll
        for (int off = 1; off < 64; off <<= 1) {
            unsigned vv = __shfl_down(acc, off, 64);
            if (lane + off < 64) acc += vv;
        }
        unsigned run = acc - ss;
        int Tl = -1; unsigned bl = 0;
        if (run < 32u && run + ch >= 32u) { Tl = 2 * lane + 1; bl = run; }
        run += ch;
        if (Tl < 0 && run < 32u && run + cl >= 32u) { Tl = 2 * lane; bl = run; }
        unsigned long long bal = __ballot(Tl >= 0);
        int src = __ffsll(bal) - 1;
        int Tv = __shfl(Tl, src, 64);
        unsigned bv = (unsigned)__shfl((int)bl, src, 64);
        if (lane == 0) { sT[row] = Tv; sBase[row] = bv; }
    }
    __syncthreads();

    float Tin[8], Tlo[8];
#pragma unroll
    for (int r = 0; r < 8; ++r) {
        int T = sT[rowloc8[r]];
        Tin[r] = (float)(T + 1);
        Tlo[r] = (T == 0) ? -3.0e38f : (float)T;
    }

    // ---- sweep 2: identical qf recompute, float-threshold emit ----
    {
        f16x8 Bh_c = *(const f16x8*)(XhbB + cp0 * 64u + akB);
        f16x8 Bl_c = *(const f16x8*)(XlbB + cp0 * 64u + akB);
        float xxj_c = xxb[cp0];
#pragma unroll 1
        for (int tt = 0; tt < 64; ++tt) {
            unsigned cp = cp0 + (unsigned)(tt << 4);
            unsigned cpn = cp0 + (unsigned)(((tt + 1) & 63) << 4);
            f16x8 Bh_n = *(const f16x8*)(XhbB + cpn * 64u + akB);
            f16x8 Bl_n = *(const f16x8*)(XlbB + cpn * 64u + akB);
            float xxj_n = xxb[cpn];
            f32x4 z = {0.f, 0.f, 0.f, 0.f};
            f32x4 u0 = MFMA16(Al0, Bl_c, z); u0 = MFMA16(Ah0, Bl_c, u0);
            f32x4 w0 = MFMA16(Al0, Bh_c, z); w0 = MFMA16(Ah0, Bh_c, w0);
            f32x4 u1 = MFMA16(Al1, Bl_c, z); u1 = MFMA16(Ah1, Bl_c, u1);
            f32x4 w1 = MFMA16(Al1, Bh_c, z); w1 = MFMA16(Ah1, Bh_c, w1);
            float bcol[8];
#pragma unroll
            for (int r = 0; r < 8; ++r) bcol[r] = __builtin_fmaf(xxj_c, scn[r], c0a[r]);
#pragma unroll
            for (int r = 0; r < 8; ++r) {
                float a = (r < 4) ? (u0[r] + w0[r]) : (u1[r - 4] + w1[r - 4]);
                float qf = __builtin_fmaf(a, sc2[r], bcol[r]);
                if (qf >= Tlo[r]) {
                    unsigned row = rowW[r] / 132u;
                    if (qf >= Tin[r]) {
                        unsigned pos = atomicAdd(&outCnt[row], 1u);
                        outIdx[row][pos] = cp;
                    } else {
                        unsigned tp = atomicAdd(&tieCnt[row], 1u);
                        if (tp < 96u) tieIdx[row][tp] = cp;
                    }
                }
            }
            Bh_c = Bh_n; Bl_c = Bl_n; xxj_c = xxj_n;
        }
    }
    __syncthreads();

    // ---- resolve boundary bucket with exact fp32 scores ----
#pragma unroll 1
    for (int rr = 0; rr < 8; ++rr) {
        int row = wv * 8 + rr;
        int gr = n0 + row;
        unsigned bA = sBase[row];
        int need = 32 - (int)bA;
        if (need <= 0) continue;
        int nt = (int)tieCnt[row]; if (nt > 96) nt = 96;
        const float* xr = xt + (bbase + gr) * 32;
        float xxi_r = xxb[gr];
        float v0 = -INFINITY, v1 = -INFINITY;
        int i0 = 0x7fffffff, i1 = 0x7fffffff;
        bool a0v = lane < nt, a1v = lane + 64 < nt;
        if (a0v) {
            int c = (int)tieIdx[row][lane];
            const float* xc = xt + (bbase + c) * 32;
            float dot = 0.f;
#pragma unroll
            for (int ch = 0; ch < 32; ch += 4) {
                float4 rv = *(const float4*)(xr + ch);
                float4 cv = *(const float4*)(xc + ch);
                dot = __builtin_fmaf(rv.x, cv.x, dot);
                dot = __builtin_fmaf(rv.y, cv.y, dot);
                dot = __builtin_fmaf(rv.z, cv.z, dot);
                dot = __builtin_fmaf(rv.w, cv.w, dot);
            }
            v0 = 2.f * dot - xxi_r - xxb[c];
            i0 = c;
        }
        if (a1v) {
            int c = (int)tieIdx[row][lane + 64];
            const float* xc = xt + (bbase + c) * 32;
            float dot = 0.f;
#pragma unroll
            for (int ch = 0; ch < 32; ch += 4) {
                float4 rv = *(const float4*)(xr + ch);
                float4 cv = *(const float4*)(xc + ch);
                dot = __builtin_fmaf(rv.x, cv.x, dot);
                dot = __builtin_fmaf(rv.y, cv.y, dot);
                dot = __builtin_fmaf(rv.z, cv.z, dot);
                dot = __builtin_fmaf(rv.w, cv.w, dot);
            }
            v1 = 2.f * dot - xxi_r - xxb[c];
            i1 = c;
        }
        for (int it = 0; it < need; ++it) {
            float bvv = -INFINITY; int bj2 = 0x7fffffff;
            if (a0v && (v0 > bvv || (v0 == bvv && i0 < bj2))) { bvv = v0; bj2 = i0; }
            if (a1v && (v1 > bvv || (v1 == bvv && i1 < bj2))) { bvv = v1; bj2 = i1; }
#pragma unroll
            for (int off = 1; off < 64; off <<= 1) {
                float ov = __shfl_xor(bvv, off, 64);
                int oj = __shfl_xor(bj2, off, 64);
                if (ov > bvv || (ov == bvv && oj < bj2)) { bvv = ov; bj2 = oj; }
            }
            if (a0v && i0 == bj2) a0v = false;
            if (a1v && i1 == bj2) a1v = false;
            if (lane == 0) outIdx[row][bA + it] = (unsigned)bj2;
        }
    }
    __syncthreads();

    for (int i = t; i < 1024; i += 256)
        idxg[(bbase + n0 + (i >> 5)) * 32 + (i & 31)] = outIdx[i >> 5][i & 31];
}

// ---------------- K4: attention gather only -> msg ----------------
__global__ __launch_bounds__(256) void k_attn(
        const float* __restrict__ Qf, const float* __restrict__ KV,
        const unsigned* __restrict__ idxg, float* __restrict__ msg) {
    int t = threadIdx.x;
    int wv = t >> 6, lane = t & 63;
    int l32 = lane & 31;
    int p = blockIdx.x * 8 + wv * 2 + (lane >> 5);
    int b = p >> 12;
    size_t bbase = (size_t)b * NN;
    const char* KVb = (const char*)(KV + bbase * 64);
    float q = Qf[(size_t)p * 32 + l32];
    int jv = (int)idxg[(size_t)p * 32 + l32];
    unsigned laneoff = (unsigned)l32 * 8u;
    float zacc = 0.f, macc = 0.f;
#pragma unroll 8
    for (int k = 0; k < 32; ++k) {
        int j = __shfl(jv, k, 32);
        unsigned off = ((unsigned)j << 8) + laneoff;
        float2 kv = *(const float2*)(KVb + off);
        float s = q * kv.x;
        s += __shfl_xor(s, 1, 8);
        s += __shfl_xor(s, 2, 8);
        s += __shfl_xor(s, 4, 8);
        zacc += s;
        macc = __builtin_fmaf(s, kv.y, macc);
    }
    float Z = 1.f / (zacc + 1e-6f);
    msg[(size_t)p * 32 + l32] = macc * Z;
}

// ---------------- K5: merge + LN1 + MLP + LN2 + residual + transpose (MFMA) ----------------
__global__ __launch_bounds__(256, 2) void k_post(
        const float* __restrict__ msg, const float* __restrict__ xt,
        const float* __restrict__ w_merge,
        const float* __restrict__ ln1_g, const float* __restrict__ ln1_b,
        const float* __restrict__ w_mlp1, const float* __restrict__ w_mlp2,
        const float* __restrict__ ln2_g, const float* __restrict__ ln2_b,
        float* __restrict__ out) {
    __shared__ _Float16 wmT[2][32][32];
    __shared__ _Float16 w1T[2][64][64];
    __shared__ _Float16 w2T[2][32][64];
    __shared__ _Float16 sPh[4][16][40], sPl[4][16][40];
    __shared__ _Float16 sHh[4][16][72], sHl[4][16][72];
    int t = threadIdx.x;
    for (int i = t; i < 1024; i += 256) {
        float v = w_merge[i]; int in = i >> 5, o = i & 31;
        _Float16 h = (_Float16)v;
        wmT[0][o][in] = h; wmT[1][o][in] = (_Float16)(v - (float)h);
    }
    for (int i = t; i < 4096; i += 256) {
        float v = w_mlp1[i]; int in = i >> 6, o = i & 63;
        _Float16 h = (_Float16)v;
        w1T[0][o][in] = h; w1T[1][o][in] = (_Float16)(v - (float)h);
    }
    for (int i = t; i < 2048; i += 256) {
        float v = w_mlp2[i]; int in = i >> 5, o = i & 31;
        _Float16 h = (_Float16)v;
        w2T[0][o][in] = h; w2T[1][o][in] = (_Float16)(v - (float)h);
    }
    int wv = t >> 6, lane = t & 63;
    int row = lane & 15, kg = lane >> 4;
    int p0 = blockIdx.x * 64 + wv * 16;
    int b = p0 >> 12;
    float g1a = ln1_g[row], b1a = ln1_b[row], g1b = ln1_g[row + 16], b1b = ln1_b[row + 16];
    float g2a = ln2_g[row], b2a = ln2_b[row], g2b = ln2_g[row + 16], b2b = ln2_b[row + 16];
    __syncthreads();

    f32x4 z4 = {0.f, 0.f, 0.f, 0.f};
    // A_msg hi/lo
    f16x8 Amh, Aml;
    {
        const float* mr = msg + (size_t)(p0 + row) * 32 + kg * 8;
#pragma unroll
        for (int j = 0; j < 8; ++j) {
            float v = mr[j];
            _Float16 h = (_Float16)v;
            Amh[j] = h; Aml[j] = (_Float16)(v - (float)h);
        }
    }
    f32x4 accM[2];
#pragma unroll
    for (int n = 0; n < 2; ++n) {
        f16x8 Bh = *(const f16x8*)&wmT[0][n * 16 + row][kg * 8];
        f16x8 Bl = *(const f16x8*)&wmT[1][n * 16 + row][kg * 8];
        f32x4 a = z4;
        a = MFMA16(Aml, Bl, a); a = MFMA16(Amh, Bl, a);
        a = MFMA16(Aml, Bh, a); a = MFMA16(Amh, Bh, a);
        accM[n] = a;
    }
    // LN1 -> msgn packed hi/lo in LDS
#pragma unroll
    for (int r = 0; r < 4; ++r) {
        float s0 = accM[0][r], s1 = accM[1][r];
        float sm = s0 + s1;
        sm += __shfl_xor(sm, 1, 64); sm += __shfl_xor(sm, 2, 64);
        sm += __shfl_xor(sm, 4, 64); sm += __shfl_xor(sm, 8, 64);
        float mean = sm * (1.f / 32.f);
        float d0 = s0 - mean, d1 = s1 - mean;
        float vv = d0 * d0 + d1 * d1;
        vv += __shfl_xor(vv, 1, 64); vv += __shfl_xor(vv, 2, 64);
        vv += __shfl_xor(vv, 4, 64); vv += __shfl_xor(vv, 8, 64);
        float rst = rsqrtf(vv * (1.f / 32.f) + 1e-5f);
        float m0 = g1a * d0 * rst + b1a;
        float m1 = g1b * d1 * rst + b1b;
        int pl = kg * 4 + r;
        _Float16 h0 = (_Float16)m0;
        sPh[wv][pl][row] = h0; sPl[wv][pl][row] = (_Float16)(m0 - (float)h0);
        _Float16 h1 = (_Float16)m1;
        sPh[wv][pl][row + 16] = h1; sPl[wv][pl][row + 16] = (_Float16)(m1 - (float)h1);
    }
    __syncthreads();
    // A_xt hi/lo
    f16x8 Axh, Axl;
    {
        const float* xr = xt + (size_t)(p0 + row) * 32 + kg * 8;
#pragma unroll
        for (int j = 0; j < 8; ++j) {
            float v = xr[j];
            _Float16 h = (_Float16)v;
            Axh[j] = h; Axl[j] = (_Float16)(v - (float)h);
        }
    }
    f16x8 Aph = *(const f16x8*)&sPh[wv][row][kg * 8];
    f16x8 Apl = *(const f16x8*)&sPl[wv][row][kg * 8];
    // mlp1 (K=64: xt | msgn), relu
    f32x4 accH[4];
#pragma unroll
    for (int n = 0; n < 4; ++n) {
        f16x8 B0h = *(const f16x8*)&w1T[0][n * 16 + row][kg * 8];
        f16x8 B0l = *(const f16x8*)&w1T[1][n * 16 + row][kg * 8];
        f16x8 B1h = *(const f16x8*)&w1T[0][n * 16 + row][32 + kg * 8];
        f16x8 B1l = *(const f16x8*)&w1T[1][n * 16 + row][32 + kg * 8];
        f32x4 a = z4;
        a = MFMA16(Axl, B0l, a); a = MFMA16(Axh, B0l, a);
        a = MFMA16(Axl, B0h, a); a = MFMA16(Axh, B0h, a);
        a = MFMA16(Apl, B1l, a); a = MFMA16(Aph, B1l, a);
        a = MFMA16(Apl, B1h, a); a = MFMA16(Aph, B1h, a);
        accH[n] = a;
    }
#pragma unroll
    for (int n = 0; n < 4; ++n) {
#pragma unroll
        for (int r = 0; r < 4; ++r) {
            float hv = fmaxf(accH[n][r], 0.f);
            int pl = kg * 4 + r;
            _Float16 hh = (_Float16)hv;
            sHh[wv][pl][n * 16 + row] = hh;
            sHl[wv][pl][n * 16 + row] = (_Float16)(hv - (float)hh);
        }
    }
    __syncthreads();
    f16x8 Hh0 = *(const f16x8*)&sHh[wv][row][kg * 8];
    f16x8 Hl0 = *(const f16x8*)&sHl[wv][row][kg * 8];
    f16x8 Hh1 = *(const f16x8*)&sHh[wv][row][32 + kg * 8];
    f16x8 Hl1 = *(const f16x8*)&sHl[wv][row][32 + kg * 8];
    f32x4 accO[2];
#pragma unroll
    for (int n = 0; n < 2; ++n) {
        f16x8 B0h = *(const f16x8*)&w2T[0][n * 16 + row][kg * 8];
        f16x8 B0l = *(const f16x8*)&w2T[1][n * 16 + row][kg * 8];
        f16x8 B1h = *(const f16x8*)&w2T[0][n * 16 + row][32 + kg * 8];
        f16x8 B1l = *(const f16x8*)&w2T[1][n * 16 + row][32 + kg * 8];
        f32x4 a = z4;
        a = MFMA16(Hl0, B0l, a); a = MFMA16(Hh0, B0l, a);
        a = MFMA16(Hl0, B0h, a); a = MFMA16(Hh0, B0h, a);
        a = MFMA16(Hl1, B1l, a); a = MFMA16(Hh1, B1l, a);
        a = MFMA16(Hl1, B1h, a); a = MFMA16(Hh1, B1h, a);
        accO[n] = a;
    }
    // LN2 + residual + transposed store
#pragma unroll
    for (int r = 0; r < 4; ++r) {
        float s0 = accO[0][r], s1 = accO[1][r];
        float sm = s0 + s1;
        sm += __shfl_xor(sm, 1, 64); sm += __shfl_xor(sm, 2, 64);
        sm += __shfl_xor(sm, 4, 64); sm += __shfl_xor(sm, 8, 64);
        float mean = sm * (1.f / 32.f);
        float d0 = s0 - mean, d1 = s1 - mean;
        float vv = d0 * d0 + d1 * d1;
        vv += __shfl_xor(vv, 1, 64); vv += __shfl_xor(vv, 2, 64);
        vv += __shfl_xor(vv, 4, 64); vv += __shfl_xor(vv, 8, 64);
        float rst = rsqrtf(vv * (1.f / 32.f) + 1e-5f);
        float o0 = g2a * d0 * rst + b2a;
        float o1 = g2b * d1 * rst + b2b;
        int pt = p0 + kg * 4 + r;
        int nb = pt & 4095;
        float xv0 = xt[(size_t)pt * 32 + row];
        float xv1 = xt[(size_t)pt * 32 + row + 16];
        out[((size_t)b * 32 + row) * 4096 + nb] = xv0 + o0;
        out[((size_t)b * 32 + row + 16) * 4096 + nb] = xv1 + o1;
    }
}

extern "C" void kernel_launch(void* const* d_in, const int* in_sizes, int n_in,
                              void* d_out, int out_size, void* d_ws, size_t ws_size,
                              hipStream_t stream) {
    const float* feat   = (const float*)d_in[0];
    const float* xyz    = (const float*)d_in[1];
    const float* w_pos1 = (const float*)d_in[2];
    const float* b_pos1 = (const float*)d_in[3];
    const float* w_pos2 = (const float*)d_in[4];
    const float* b_pos2 = (const float*)d_in[5];
    const float* w_q    = (const float*)d_in[6];
    const float* w_k    = (const float*)d_in[7];
    const float* w_v    = (const float*)d_in[8];
    const float* w_mg   = (const float*)d_in[9];
    const float* ln1_g  = (const float*)d_in[10];
    const float* ln1_b  = (const float*)d_in[11];
    const float* w_mlp1 = (const float*)d_in[12];
    const float* w_mlp2 = (const float*)d_in[13];
    const float* ln2_g  = (const float*)d_in[14];
    const float* ln2_b  = (const float*)d_in[15];
    float* ws = (float*)d_ws;
    float* xt = ws + OFF_XT;
    float* Qf = ws + OFF_QF;
    float* KVp = ws + OFF_KV;
    float* xx = ws + OFF_XX;
    unsigned* idxg = (unsigned*)(ws + OFF_IDX);
    _Float16* Xh = (_Float16*)(ws + OFF_XH);
    _Float16* Xl = (_Float16*)(ws + OFF_XL);
    float* msg = ws + OFF_MSG;
    float* out = (float*)d_out;

    k_transpose<<<dim3(64, 8), 256, 0, stream>>>(feat, xt, Xh, Xl, xx);
    k_prep<<<1024, 256, 0, stream>>>(xt, xyz, w_pos1, b_pos1, w_pos2, b_pos2,
                                     w_q, w_k, w_v, Qf, KVp);
    k_knn<<<1024, 256, 0, stream>>>(Xh, Xl, xt, xx, idxg);
    k_attn<<<4096, 256, 0, stream>>>(Qf, KVp, idxg, msg);
    k_post<<<512, 256, 0, stream>>>(msg, xt, w_mg, ln1_g, ln1_b,
                                    w_mlp1, w_mlp2, ln2_g, ln2_b, out);
}